// Round 11
// baseline (192.742 us; speedup 1.0000x reference)
//
#include <hip/hip_runtime.h>
#include <cstddef>
#include <cstdint>

#define D_EMB  768
#define NHEAD  12
#define HDIM   64
#define THEAD  32
#define SEQ    2048
#define BATCH  2
#define NROW   (BATCH*SEQ)   // 4096
#define HID4   3072

typedef unsigned short u16;
typedef __bf16 bf16x8 __attribute__((ext_vector_type(8)));
typedef float  f32x4  __attribute__((ext_vector_type(4)));
typedef float  f32x16 __attribute__((ext_vector_type(16)));
typedef unsigned short u16x8 __attribute__((ext_vector_type(8)));

__device__ __forceinline__ u16 f2bf(float f) {
    unsigned u = __builtin_bit_cast(unsigned, f);
    return (u16)((u + 0x7FFFu + ((u >> 16) & 1u)) >> 16);
}
__device__ __forceinline__ float bf2f(u16 h) {
    return __builtin_bit_cast(float, (unsigned)h << 16);
}
__device__ __forceinline__ u16 cvt_bf(float f) {
    return __builtin_bit_cast(u16, (__bf16)f);
}

// global -> LDS direct copy, 16B per lane (used by GEMMs; attention now
// reg-stages to allow an 8B-granule XOR swizzle).
__device__ __forceinline__ void gload_lds16(const void* g, void* l) {
    __builtin_amdgcn_global_load_lds(
        reinterpret_cast<const __attribute__((address_space(1))) void*>(
            reinterpret_cast<uintptr_t>(g)),
        reinterpret_cast<__attribute__((address_space(3))) void*>(
            (uint32_t)reinterpret_cast<uintptr_t>(l)),
        16, 0, 0);
}

// ---------------------------------------------------------------------------
// Fused prep: all weight transposes + x cast + bias concat in one launch.
// ---------------------------------------------------------------------------
__device__ __forceinline__ void tcast(float (*t)[33], const float* __restrict__ W,
                                      u16* __restrict__ WT, int K, int M,
                                      int mt, int kt)
{
    const int m0 = mt * 32, k0 = kt * 32;
    const int tx = threadIdx.x & 31, ty = threadIdx.x >> 5;
#pragma unroll
    for (int i = 0; i < 32; i += 8)
        t[ty + i][tx] = W[(size_t)(k0 + ty + i) * M + m0 + tx];
    __syncthreads();
#pragma unroll
    for (int i = 0; i < 32; i += 8)
        WT[(size_t)(m0 + ty + i) * K + k0 + tx] = f2bf(t[tx][ty + i]);
}

__global__ __launch_bounds__(256)
void prep(const float* __restrict__ Wq, const float* __restrict__ Wk,
          const float* __restrict__ Wv, const float* __restrict__ Wo,
          const float* __restrict__ W1, const float* __restrict__ W2,
          const float* __restrict__ bq, const float* __restrict__ bk,
          const float* __restrict__ bv, const float* __restrict__ x,
          u16* __restrict__ WqkvoT, u16* __restrict__ W1T,
          u16* __restrict__ W2T, u16* __restrict__ xb,
          float* __restrict__ bqkv)
{
    __shared__ float t[32][33];
    const int bid = blockIdx.x;
    if (bid < 2304) {                       // Wq/Wk/Wv/Wo 768x768 -> [z*768+m][k]
        const int z = bid / 576, r = bid % 576;
        const float* W = z == 0 ? Wq : z == 1 ? Wk : z == 2 ? Wv : Wo;
        tcast(t, W, WqkvoT + (size_t)z * 768 * 768, 768, 768, r % 24, r / 24);
    } else if (bid < 4608) {                // W1 [768][3072] -> [3072][768]
        const int r = bid - 2304;
        tcast(t, W1, W1T, 768, 3072, r % 96, r / 96);
    } else if (bid < 6912) {                // W2 [3072][768] -> [768][3072]
        const int r = bid - 4608;
        tcast(t, W2, W2T, 3072, 768, r % 24, r / 24);
    } else if (bid < 8448) {                // cast x -> bf16
        const int i = (bid - 6912) * 2048 + threadIdx.x * 8;
        const float4 a = *reinterpret_cast<const float4*>(x + i);
        const float4 b = *reinterpret_cast<const float4*>(x + i + 4);
        u16x8 h;
        h[0] = f2bf(a.x); h[1] = f2bf(a.y); h[2] = f2bf(a.z); h[3] = f2bf(a.w);
        h[4] = f2bf(b.x); h[5] = f2bf(b.y); h[6] = f2bf(b.z); h[7] = f2bf(b.w);
        *reinterpret_cast<u16x8*>(xb + i) = h;
    } else {                                // concat qkv bias
        const int i = (bid - 8448) * 256 + threadIdx.x;
        if (i < 2304)
            bqkv[i] = i < 768 ? bq[i] : (i < 1536 ? bk[i - 768] : bv[i - 1536]);
    }
}

// ---------------------------------------------------------------------------
// bf16 MFMA GEMM: C[Mr x N] = A[Mr x K] @ B[N x K]^T + bias
// 128x128 tile, BK=32, 4 waves, double-buffered LDS.
// EPI: 2 = gelu+bf16 out, 3 = QKV mode (QK bf16 [row][1536], V written
//      transposed to VT[b][h][d][tok], natural token order).
// ---------------------------------------------------------------------------
template<int EPI>
__global__ __launch_bounds__(256)
void gemm_bf16(const u16* __restrict__ A, const u16* __restrict__ B,
               const float* __restrict__ bias, void* __restrict__ Cp,
               u16* __restrict__ VTp, int K, int N)
{
    __shared__ u16 As[2][128 * 32];
    __shared__ u16 Bs[2][128 * 32];
    const int tid  = threadIdx.x;
    const int lane = tid & 63;
    const int w    = tid >> 6;
    const int m0 = blockIdx.x * 128, n0 = blockIdx.y * 128;
    const int wr = (w >> 1) << 6, wc = (w & 1) << 6;

    const int seg0 = (w << 11) + lane * 16;
    const int row0 = seg0 >> 6, cb0 = (seg0 & 63) >> 1;
    const int seg1 = seg0 + 1024;
    const int row1 = seg1 >> 6, cb1 = (seg1 & 63) >> 1;
    const u16* a0 = A + (size_t)(m0 + row0) * K + cb0;
    const u16* a1 = A + (size_t)(m0 + row1) * K + cb1;
    const u16* b0 = B + (size_t)(n0 + row0) * K + cb0;
    const u16* b1 = B + (size_t)(n0 + row1) * K + cb1;
    const int lo0 = (w * 2 + 0) << 9;
    const int lo1 = (w * 2 + 1) << 9;

    int aIdx[4], bIdx[4];
#pragma unroll
    for (int i = 0; i < 4; ++i) {
        aIdx[i] = (wr + i * 16 + (lane & 15)) * 32 + ((lane >> 4) << 3);
        bIdx[i] = (wc + i * 16 + (lane & 15)) * 32 + ((lane >> 4) << 3);
    }

    f32x4 acc[4][4];
#pragma unroll
    for (int i = 0; i < 4; ++i)
#pragma unroll
        for (int j = 0; j < 4; ++j)
#pragma unroll
            for (int q = 0; q < 4; ++q) acc[i][j][q] = 0.f;

    gload_lds16(a0, &As[0][lo0]);
    gload_lds16(a1, &As[0][lo1]);
    gload_lds16(b0, &Bs[0][lo0]);
    gload_lds16(b1, &Bs[0][lo1]);
    __syncthreads();

    int cur = 0;
    for (int k0 = 0; k0 < K; k0 += 32) {
        if (k0 + 32 < K) {
            gload_lds16(a0 + k0 + 32, &As[cur ^ 1][lo0]);
            gload_lds16(a1 + k0 + 32, &As[cur ^ 1][lo1]);
            gload_lds16(b0 + k0 + 32, &Bs[cur ^ 1][lo0]);
            gload_lds16(b1 + k0 + 32, &Bs[cur ^ 1][lo1]);
        }
        bf16x8 af[4], bv[4];
#pragma unroll
        for (int i = 0; i < 4; ++i)
            af[i] = *reinterpret_cast<const bf16x8*>(&As[cur][aIdx[i]]);
#pragma unroll
        for (int j = 0; j < 4; ++j)
            bv[j] = *reinterpret_cast<const bf16x8*>(&Bs[cur][bIdx[j]]);
#pragma unroll
        for (int i = 0; i < 4; ++i)
#pragma unroll
            for (int j = 0; j < 4; ++j)
                acc[i][j] = __builtin_amdgcn_mfma_f32_16x16x32_bf16(
                    af[i], bv[j], acc[i][j], 0, 0, 0);
        __syncthreads();
        cur ^= 1;
    }

#pragma unroll
    for (int i = 0; i < 4; ++i) {
#pragma unroll
        for (int q = 0; q < 4; ++q) {
            const int row = m0 + wr + i * 16 + ((lane >> 4) << 2) + q;
#pragma unroll
            for (int j = 0; j < 4; ++j) {
                const int col = n0 + wc + j * 16 + (lane & 15);
                float v = acc[i][j][q] + bias[col];
                if (EPI == 2) {
                    // gelu(tanh form) == v * sigmoid(2*0.79788456*(v+0.044715 v^3))
                    const float z = 1.5957691216057308f *
                                    (v + 0.044715f * v * v * v);
                    const float e = __builtin_amdgcn_exp2f(z * -1.4426950408889634f);
                    v = v * __builtin_amdgcn_rcpf(1.f + e);
                    ((u16*)Cp)[(size_t)row * N + col] = cvt_bf(v);
                } else {   // EPI == 3: QKV
                    if (n0 < 1536) {
                        ((u16*)Cp)[(size_t)row * 1536 + col] = cvt_bf(v);
                    } else {
                        const int c2 = col - 1536;
                        const int hh = c2 >> 6, dd = c2 & 63;
                        const int bb = row >> 11, tok = row & 2047;
                        VTp[((size_t)(bb * NHEAD + hh) * HDIM + dd) * SEQ + tok]
                            = cvt_bf(v);
                    }
                }
            }
        }
    }
}

// ---------------------------------------------------------------------------
// BM=64 x BN=128 split-K GEMM for N=768 shapes, fp32 out.
// grid.z = 2: z=0 computes K-half 0 (+bias) -> C0; z=1 K-half 1 -> C1.
// ---------------------------------------------------------------------------
__global__ __launch_bounds__(256)
void gemm_n64(const u16* __restrict__ A, const u16* __restrict__ B,
              const float* __restrict__ bias, float* __restrict__ C0,
              float* __restrict__ C1, int Khalf, int Ktot, int N)
{
    __shared__ u16 As[2][64 * 32];
    __shared__ u16 Bs[2][128 * 32];
    const int tid  = threadIdx.x;
    const int lane = tid & 63;
    const int w    = tid >> 6;
    const int l15  = lane & 15;
    const int g    = lane >> 4;
    const int m0 = blockIdx.x * 64, n0 = blockIdx.y * 128;
    const int zz = blockIdx.z;
    const int kbase = zz * Khalf;
    float* __restrict__ C = zz ? C1 : C0;

    const int segA = (w << 10) + lane * 16;
    const int rowA = segA >> 6, cbA = (segA & 63) >> 1;
    const u16* aP = A + (size_t)(m0 + rowA) * Ktot + kbase + cbA;
    const int loA = w << 9;
    const int seg0 = (w << 11) + lane * 16;
    const int row0 = seg0 >> 6, cb0 = (seg0 & 63) >> 1;
    const int seg1 = seg0 + 1024;
    const int row1 = seg1 >> 6, cb1 = (seg1 & 63) >> 1;
    const u16* b0 = B + (size_t)(n0 + row0) * Ktot + kbase + cb0;
    const u16* b1 = B + (size_t)(n0 + row1) * Ktot + kbase + cb1;
    const int lo0 = w << 10, lo1 = (w << 10) + 512;

    int aIdx[4], bIdx[2];
#pragma unroll
    for (int i = 0; i < 4; ++i) aIdx[i] = (i * 16 + l15) * 32 + (g << 3);
#pragma unroll
    for (int j = 0; j < 2; ++j) bIdx[j] = ((w << 5) + j * 16 + l15) * 32 + (g << 3);

    f32x4 acc[4][2];
#pragma unroll
    for (int i = 0; i < 4; ++i)
#pragma unroll
        for (int j = 0; j < 2; ++j)
#pragma unroll
            for (int q = 0; q < 4; ++q) acc[i][j][q] = 0.f;

    gload_lds16(aP, &As[0][loA]);
    gload_lds16(b0, &Bs[0][lo0]);
    gload_lds16(b1, &Bs[0][lo1]);
    __syncthreads();

    int cur = 0;
    for (int k0 = 0; k0 < Khalf; k0 += 32) {
        if (k0 + 32 < Khalf) {
            gload_lds16(aP + k0 + 32, &As[cur ^ 1][loA]);
            gload_lds16(b0 + k0 + 32, &Bs[cur ^ 1][lo0]);
            gload_lds16(b1 + k0 + 32, &Bs[cur ^ 1][lo1]);
        }
        bf16x8 af[4], bv[2];
#pragma unroll
        for (int i = 0; i < 4; ++i)
            af[i] = *reinterpret_cast<const bf16x8*>(&As[cur][aIdx[i]]);
#pragma unroll
        for (int j = 0; j < 2; ++j)
            bv[j] = *reinterpret_cast<const bf16x8*>(&Bs[cur][bIdx[j]]);
#pragma unroll
        for (int i = 0; i < 4; ++i)
#pragma unroll
            for (int j = 0; j < 2; ++j)
                acc[i][j] = __builtin_amdgcn_mfma_f32_16x16x32_bf16(
                    af[i], bv[j], acc[i][j], 0, 0, 0);
        __syncthreads();
        cur ^= 1;
    }

#pragma unroll
    for (int i = 0; i < 4; ++i) {
#pragma unroll
        for (int q = 0; q < 4; ++q) {
            const int row = m0 + i * 16 + (g << 2) + q;
#pragma unroll
            for (int j = 0; j < 2; ++j) {
                const int col = n0 + (w << 5) + j * 16 + l15;
                const float bb = zz ? 0.f : bias[col];
                C[(size_t)row * N + col] = acc[i][j][q] + bb;
            }
        }
    }
}

// ---------------------------------------------------------------------------
// MFMA flash attention, 32x32x16, swapped QK^T (S^T = K x Q^T), P IN REGS.
// Conflict-free LDS: reg-staged K/V with 8B-granule XOR swizzle
// G = g ^ (row&15) -> all b64 reads 2-way (free). PV contraction uses the
// key-permutation pi(hi*8+j) = (j&3)+8*(j>>2)+4*hi so the S^T C-layout regs
// ARE the PV A-fragment (no P LDS, no cross-lane ops). Split-KV z=2 +
// attn_merge. Static-max softmax (exp2-domain, Q pre-scaled).
// ---------------------------------------------------------------------------
#define SM_SCALE 0.18033688011112042f   // log2(e)/8

__global__ __launch_bounds__(256)
void attn_mfma(const u16* __restrict__ QK, const u16* __restrict__ VT,
               u16* __restrict__ O0, u16* __restrict__ O1,
               float* __restrict__ Sp)
{
    __shared__ u16 Ks[2][64 * 64];   // [key][d-granule swizzled]
    __shared__ u16 Vs[2][64 * 64];   // [d][key-granule swizzled]

    const int tid  = threadIdx.x;
    const int lane = tid & 63;
    const int w    = tid >> 6;           // 0..3
    const int l31  = lane & 31;
    const int hi   = lane >> 5;          // 0..1
    const int m15  = l31 & 15;
    const int bh   = blockIdx.x;
    const int b    = bh / NHEAD, h = bh % NHEAD;
    const int q0   = blockIdx.y * 128;
    const int z    = blockIdx.z;
    const int keybase = z * 1024;
    const int bS   = b * SEQ;

    // ---- Q B-fragments (eta+scale folded): lane q = w*32+l31 ----
    bf16x8 bq[4];
    {
        const u16* Qg = QK + (size_t)(bS + q0 + w * 32 + l31) * 1536 + h * HDIM;
#pragma unroll
        for (int s = 0; s < 4; ++s) {
            const u16x8 hq = *reinterpret_cast<const u16x8*>(
                Qg + s * 16 + hi * 8);
            const float sc = (s < 2) ? -SM_SCALE : SM_SCALE;  // d<32 <=> s<2
            u16x8 hs;
#pragma unroll
            for (int j = 0; j < 8; ++j)
                hs[j] = cvt_bf(bf2f(hq[j]) * sc);
            bq[s] = __builtin_bit_cast(bf16x8, hs);
        }
    }

    // ---- staging geometry: wave w stages rows 16w..16w+15 of K and V ----
    const int rj = lane >> 3, cj = lane & 7;     // row-in-8, 16B chunk
    const int R0 = 16 * w + rj, R1 = R0 + 8;
    const u16* gK0 = QK + (size_t)(bS + keybase + R0) * 1536 + 768 + h * HDIM + cj * 8;
    const u16* gK1 = QK + (size_t)(bS + keybase + R1) * 1536 + 768 + h * HDIM + cj * 8;
    const u16* gV0 = VT + ((size_t)(b * NHEAD + h) * HDIM + R0) * SEQ + keybase + cj * 8;
    const u16* gV1 = VT + ((size_t)(b * NHEAD + h) * HDIM + R1) * SEQ + keybase + cj * 8;
    // LDS write offsets (u16 units), granule-XOR swizzled
    const int wo00 = R0 * 64 + 4 * ((2 * cj + 0) ^ (R0 & 15));
    const int wo01 = R0 * 64 + 4 * ((2 * cj + 1) ^ (R0 & 15));
    const int wo10 = R1 * 64 + 4 * ((2 * cj + 0) ^ (R1 & 15));
    const int wo11 = R1 * 64 + 4 * ((2 * cj + 1) ^ (R1 & 15));

    uint4 sK0, sK1, sV0, sV1;
#define LOADSTAGE(kt)                                                        \
    do {                                                                     \
        sK0 = *reinterpret_cast<const uint4*>(gK0 + (size_t)(kt) * 1536);    \
        sK1 = *reinterpret_cast<const uint4*>(gK1 + (size_t)(kt) * 1536);    \
        sV0 = *reinterpret_cast<const uint4*>(gV0 + (kt));                   \
        sV1 = *reinterpret_cast<const uint4*>(gV1 + (kt));                   \
    } while (0)
#define WRITESTAGE(c)                                                        \
    do {                                                                     \
        *reinterpret_cast<uint2*>(&Ks[c][wo00]) = make_uint2(sK0.x, sK0.y);  \
        *reinterpret_cast<uint2*>(&Ks[c][wo01]) = make_uint2(sK0.z, sK0.w);  \
        *reinterpret_cast<uint2*>(&Ks[c][wo10]) = make_uint2(sK1.x, sK1.y);  \
        *reinterpret_cast<uint2*>(&Ks[c][wo11]) = make_uint2(sK1.z, sK1.w);  \
        *reinterpret_cast<uint2*>(&Vs[c][wo00]) = make_uint2(sV0.x, sV0.y);  \
        *reinterpret_cast<uint2*>(&Vs[c][wo01]) = make_uint2(sV0.z, sV0.w);  \
        *reinterpret_cast<uint2*>(&Vs[c][wo10]) = make_uint2(sV1.x, sV1.y);  \
        *reinterpret_cast<uint2*>(&Vs[c][wo11]) = make_uint2(sV1.z, sV1.w);  \
    } while (0)

    f32x16 accO[2];
#pragma unroll
    for (int dt = 0; dt < 2; ++dt)
#pragma unroll
        for (int r = 0; r < 16; ++r) accO[dt][r] = 0.f;
    float psum = 0.f;

    LOADSTAGE(0);
    WRITESTAGE(0);
    __syncthreads();
    int cur = 0;

    for (int kt = 0; kt < 1024; kt += 64) {
        if (kt + 64 < 1024) LOADSTAGE(kt + 64);   // issue early (T14)

        // ---- S^T = K x Q^T: A=K rows (keys), B=Q; C col = q = l31 ----
        f32x16 sac[2];
        __builtin_amdgcn_s_setprio(1);
#pragma unroll
        for (int t = 0; t < 2; ++t) {
#pragma unroll
            for (int r = 0; r < 16; ++r) sac[t][r] = 0.f;
            const int krow = (t * 32 + l31) * 64;
#pragma unroll
            for (int s = 0; s < 4; ++s) {
                const int g0 = (4 * s + 2 * hi) ^ m15;
                const uint2 ra = *reinterpret_cast<const uint2*>(
                    &Ks[cur][krow + 4 * g0]);
                const uint2 rb = *reinterpret_cast<const uint2*>(
                    &Ks[cur][krow + 4 * (g0 ^ 1)]);
                const bf16x8 ak = __builtin_bit_cast(
                    bf16x8, make_uint4(ra.x, ra.y, rb.x, rb.y));
                sac[t] = __builtin_amdgcn_mfma_f32_32x32x16_bf16(
                    ak, bq[s], sac[t], 0, 0, 0);
            }
        }
        __builtin_amdgcn_s_setprio(0);

        // ---- P = exp2(S') in registers; lane-local row sums ----
        u16x8 pk[4];
#pragma unroll
        for (int t = 0; t < 2; ++t)
#pragma unroll
            for (int r = 0; r < 16; ++r) {
                const float ev = __builtin_amdgcn_exp2f(sac[t][r]);
                psum += ev;
                pk[2 * t + (r >> 3)][r & 7] = cvt_bf(ev);
            }

        // ---- O += P @ V: A = P regs (pi-permuted), B = V from LDS ----
        __builtin_amdgcn_s_setprio(1);
#pragma unroll
        for (int t = 0; t < 2; ++t)
#pragma unroll
            for (int u = 0; u < 2; ++u) {
                const bf16x8 ap = __builtin_bit_cast(bf16x8, pk[2 * t + u]);
#pragma unroll
                for (int dt = 0; dt < 2; ++dt) {
                    const int vrow = (dt * 32 + l31) * 64;
                    const int g0 = (8 * t + 4 * u + hi) ^ m15;
                    const int g1 = (8 * t + 4 * u + 2 + hi) ^ m15;
                    const uint2 ra = *reinterpret_cast<const uint2*>(
                        &Vs[cur][vrow + 4 * g0]);
                    const uint2 rb = *reinterpret_cast<const uint2*>(
                        &Vs[cur][vrow + 4 * g1]);
                    const bf16x8 bv = __builtin_bit_cast(
                        bf16x8, make_uint4(ra.x, ra.y, rb.x, rb.y));
                    accO[dt] = __builtin_amdgcn_mfma_f32_32x32x16_bf16(
                        ap, bv, accO[dt], 0, 0, 0);
                }
            }
        __builtin_amdgcn_s_setprio(0);

        if (kt + 64 < 1024) WRITESTAGE(cur ^ 1);
        __syncthreads();
        cur ^= 1;
    }

    // ---- store unnormalized bf16 O-partial + f32 sum ----
    psum += __shfl_xor(psum, 32);
    u16* __restrict__ Oz = z ? O1 : O0;
#pragma unroll
    for (int dt = 0; dt < 2; ++dt)
#pragma unroll
        for (int r = 0; r < 16; ++r) {
            const int qr = q0 + w * 32 + (r & 3) + 8 * (r >> 2) + 4 * hi;
            Oz[(size_t)(bS + qr) * D_EMB + h * HDIM + dt * 32 + l31]
                = cvt_bf(accO[dt][r]);
        }
    if (lane < 32)
        Sp[(size_t)z * (BATCH * NHEAD * SEQ) + (b * NHEAD + h) * SEQ
           + q0 + w * 32 + l31] = psum;
#undef LOADSTAGE
#undef WRITESTAGE
}

// ---------------------------------------------------------------------------
// Merge split-KV partials: Ab = (O0 + O1) / (S0 + S1), bf16 out.
// ---------------------------------------------------------------------------
__global__ __launch_bounds__(256)
void attn_merge(const u16* __restrict__ O0, const u16* __restrict__ O1,
                const float* __restrict__ Sp, u16* __restrict__ Ab)
{
    const int gid = blockIdx.x * 256 + threadIdx.x;   // ND/8 threads
    const size_t e = (size_t)gid * 8;
    const int row = gid / 96;            // 96 8-chunks per 768-row
    const int cc  = gid % 96;
    const int h   = cc >> 3;
    const int b   = row >> 11, q = row & 2047;
    const int si  = (b * NHEAD + h) * SEQ + q;
    const float s = Sp[si] + Sp[(size_t)(BATCH * NHEAD * SEQ) + si];
    const float inv = __builtin_amdgcn_rcpf(s);
    const u16x8 a = *reinterpret_cast<const u16x8*>(O0 + e);
    const u16x8 c = *reinterpret_cast<const u16x8*>(O1 + e);
    u16x8 o;
#pragma unroll
    for (int j = 0; j < 8; ++j)
        o[j] = cvt_bf((bf2f(a[j]) + bf2f(c[j])) * inv);
    *reinterpret_cast<u16x8*>(Ab + e) = o;
}

// ---------------------------------------------------------------------------
// Minkowski LN over 384/384 split with TWO residual inputs:
// Out = LN(X + R1 + R2) * g + b.
// XBF: X input is bf16. WF32: write fp32 Out. OutB optional bf16 out.
// ---------------------------------------------------------------------------
template<int XBF, int WF32>
__global__ __launch_bounds__(256)
void mink_ln(const void* __restrict__ Xp, const float* __restrict__ R1,
             const float* __restrict__ R2,
             const float* __restrict__ gt, const float* __restrict__ bt,
             const float* __restrict__ gs, const float* __restrict__ bs,
             float* __restrict__ Out, u16* __restrict__ OutB, int nrows)
{
    const int wid  = (int)((blockIdx.x * 256 + threadIdx.x) >> 6);
    const int lane = threadIdx.x & 63;
    const int row  = wid >> 1, half = wid & 1;
    if (row >= nrows) return;

    const float* g  = half ? gs : gt;
    const float* bb = half ? bs : bt;
    const size_t base = (size_t)row * D_EMB + half * 384;

    float v[6];
    float sum = 0.f;
#pragma unroll
    for (int i = 0; i < 6; ++i) {
        const size_t e = base + i * 64 + lane;
        const float xv = XBF ? bf2f(((const u16*)Xp)[e]) : ((const float*)Xp)[e];
        const float t = xv + R1[e] + R2[e];
        v[i] = t; sum += t;
    }
#pragma unroll
    for (int off = 32; off; off >>= 1) sum += __shfl_xor(sum, off);
    const float mean = sum * (1.f / 384.f);

    float ss = 0.f;
#pragma unroll
    for (int i = 0; i < 6; ++i) { const float d = v[i] - mean; ss += d * d; }
#pragma unroll
    for (int off = 32; off; off >>= 1) ss += __shfl_xor(ss, off);
    const float rstd = rsqrtf(ss * (1.f / 384.f) + 1e-5f);

#pragma unroll
    for (int i = 0; i < 6; ++i) {
        const int e = i * 64 + lane;
        const float o = (v[i] - mean) * rstd * g[e] + bb[e];
        if (WF32) Out[base + e] = o;
        if (OutB) OutB[base + e] = cvt_bf(o);
    }
}

// ---------------------------------------------------------------------------
extern "C" void kernel_launch(void* const* d_in, const int* in_sizes, int n_in,
                              void* d_out, int out_size, void* d_ws, size_t ws_size,
                              hipStream_t stream)
{
    const float* x   = (const float*)d_in[0];
    const float* Wq  = (const float*)d_in[1];
    const float* bq  = (const float*)d_in[2];
    const float* Wk  = (const float*)d_in[3];
    const float* bk  = (const float*)d_in[4];
    const float* Wv  = (const float*)d_in[5];
    const float* bv  = (const float*)d_in[6];
    const float* Wo  = (const float*)d_in[7];
    const float* bo  = (const float*)d_in[8];
    const float* g1t = (const float*)d_in[9];
    const float* b1t = (const float*)d_in[10];
    const float* g1s = (const float*)d_in[11];
    const float* b1s = (const float*)d_in[12];
    const float* W1  = (const float*)d_in[13];
    const float* bb1 = (const float*)d_in[14];
    const float* W2  = (const float*)d_in[15];
    const float* bb2 = (const float*)d_in[16];
    const float* g2t = (const float*)d_in[17];
    const float* b2t = (const float*)d_in[18];
    const float* g2s = (const float*)d_in[19];
    const float* b2s = (const float*)d_in[20];
    float* out = (float*)d_out;

    const size_t ND = (size_t)NROW * D_EMB;   // 3,145,728
    u16* WqkvoT = (u16*)d_ws;                 // [3072][768] rows q,k,v,o
    u16* W1T = WqkvoT + 2359296;              // [3072][768]
    u16* W2T = W1T + 2359296;                 // [768][3072]
    u16* xb  = W2T + 2359296;                 // ND (x bf16, then X1 bf16)
    u16* QKb = xb + ND;                       // [4096][1536] q|k
    u16* VTb = QKb + (size_t)NROW * 1536;     // [2][12][64][2048] natural
    u16* Ab  = VTb + ND;                      // ND (attn out bf16)
    u16* Hb  = QKb;                           // [4096][3072] over QKb+VTb+Ab
    float* QKf  = (float*)QKb;                // Wo split-K partial#2 (QK dead)
    float* AoF  = (float*)(Ab + ND);          // ND fp32 (Wo p1, then W2 p1)
    float* bqkv = AoF;                        // 2304 f32, dead before attn
    u16* Op0 = (u16*)AoF;                     // attn O-partials overlay AoF
    u16* Op1 = Op0 + ND;
    float* Sp = (float*)xb;                   // sums: xb content dead post-QKV

    const dim3 blk(256);

    prep<<<8457, blk, 0, stream>>>(Wq, Wk, Wv, Wo, W1, W2, bq, bk, bv, x,
                                   WqkvoT, W1T, W2T, xb, bqkv);

    // fused QKV projection (writes QKb + transposed V, natural order)
    gemm_bf16<3><<<dim3(32, 18), blk, 0, stream>>>(xb, WqkvoT, bqkv, QKb, VTb,
                                                   768, 2304);
    // split-KV attention + merge
    attn_mfma<<<dim3(BATCH * NHEAD, SEQ / 128, 2), blk, 0, stream>>>(
        QKb, VTb, Op0, Op1, Sp);
    attn_merge<<<(int)(ND / 8 / 256), blk, 0, stream>>>(Op0, Op1, Sp, Ab);

    // Wo projection, split-K=2: p1 -> AoF (+bias), p2 -> QKf (QK region dead)
    gemm_n64<<<dim3(64, 6, 2), blk, 0, stream>>>(
        Ab, WqkvoT + (size_t)2304 * 768, bo, AoF, QKf, 384, 768, 768);
    // LN1: X1 (bf16 only) -> xb
    mink_ln<0, 0><<<2048, blk, 0, stream>>>(x, AoF, QKf, g1t, b1t, g1s, b1s,
                                            nullptr, xb, NROW);
    gemm_bf16<2><<<dim3(32, 24), blk, 0, stream>>>(xb, W1T, bb1, Hb, nullptr,
                                                   768, 3072);
    // W2, split-K=2: p1 -> AoF (+bias), p2 -> out (overwritten by LN2 after read)
    gemm_n64<<<dim3(64, 6, 2), blk, 0, stream>>>(
        Hb, W2T, bb2, AoF, out, 1536, 3072, 768);
    mink_ln<1, 1><<<2048, blk, 0, stream>>>(xb, AoF, out, g2t, b2t, g2s, b2s,
                                            out, nullptr, NROW);
}

// Round 12
// 183.521 us; speedup vs baseline: 1.0502x; 1.0502x over previous
//
#include <hip/hip_runtime.h>
#include <cstddef>
#include <cstdint>

#define D_EMB  768
#define NHEAD  12
#define HDIM   64
#define THEAD  32
#define SEQ    2048
#define BATCH  2
#define NROW   (BATCH*SEQ)   // 4096
#define HID4   3072

typedef unsigned short u16;
typedef __bf16 bf16x8 __attribute__((ext_vector_type(8)));
typedef float  f32x4  __attribute__((ext_vector_type(4)));
typedef float  f32x16 __attribute__((ext_vector_type(16)));
typedef unsigned short u16x8 __attribute__((ext_vector_type(8)));

__device__ __forceinline__ u16 f2bf(float f) {
    unsigned u = __builtin_bit_cast(unsigned, f);
    return (u16)((u + 0x7FFFu + ((u >> 16) & 1u)) >> 16);
}
__device__ __forceinline__ float bf2f(u16 h) {
    return __builtin_bit_cast(float, (unsigned)h << 16);
}
__device__ __forceinline__ u16 cvt_bf(float f) {
    return __builtin_bit_cast(u16, (__bf16)f);
}

// global -> LDS direct copy, 16B per lane. LDS dst is wave-uniform base;
// HW writes base + lane*16. Global src is per-lane.
__device__ __forceinline__ void gload_lds16(const void* g, void* l) {
    __builtin_amdgcn_global_load_lds(
        reinterpret_cast<const __attribute__((address_space(1))) void*>(
            reinterpret_cast<uintptr_t>(g)),
        reinterpret_cast<__attribute__((address_space(3))) void*>(
            (uint32_t)reinterpret_cast<uintptr_t>(l)),
        16, 0, 0);
}

// ---------------------------------------------------------------------------
// Fused prep: all weight transposes + x cast + bias concat in one launch.
// ---------------------------------------------------------------------------
__device__ __forceinline__ void tcast(float (*t)[33], const float* __restrict__ W,
                                      u16* __restrict__ WT, int K, int M,
                                      int mt, int kt)
{
    const int m0 = mt * 32, k0 = kt * 32;
    const int tx = threadIdx.x & 31, ty = threadIdx.x >> 5;
#pragma unroll
    for (int i = 0; i < 32; i += 8)
        t[ty + i][tx] = W[(size_t)(k0 + ty + i) * M + m0 + tx];
    __syncthreads();
#pragma unroll
    for (int i = 0; i < 32; i += 8)
        WT[(size_t)(m0 + ty + i) * K + k0 + tx] = f2bf(t[tx][ty + i]);
}

__global__ __launch_bounds__(256)
void prep(const float* __restrict__ Wq, const float* __restrict__ Wk,
          const float* __restrict__ Wv, const float* __restrict__ Wo,
          const float* __restrict__ W1, const float* __restrict__ W2,
          const float* __restrict__ bq, const float* __restrict__ bk,
          const float* __restrict__ bv, const float* __restrict__ x,
          u16* __restrict__ WqkvoT, u16* __restrict__ W1T,
          u16* __restrict__ W2T, u16* __restrict__ xb,
          float* __restrict__ bqkv)
{
    __shared__ float t[32][33];
    const int bid = blockIdx.x;
    if (bid < 2304) {                       // Wq/Wk/Wv/Wo 768x768 -> [z*768+m][k]
        const int z = bid / 576, r = bid % 576;
        const float* W = z == 0 ? Wq : z == 1 ? Wk : z == 2 ? Wv : Wo;
        tcast(t, W, WqkvoT + (size_t)z * 768 * 768, 768, 768, r % 24, r / 24);
    } else if (bid < 4608) {                // W1 [768][3072] -> [3072][768]
        const int r = bid - 2304;
        tcast(t, W1, W1T, 768, 3072, r % 96, r / 96);
    } else if (bid < 6912) {                // W2 [3072][768] -> [768][3072]
        const int r = bid - 4608;
        tcast(t, W2, W2T, 3072, 768, r % 24, r / 24);
    } else if (bid < 8448) {                // cast x -> bf16
        const int i = (bid - 6912) * 2048 + threadIdx.x * 8;
        const float4 a = *reinterpret_cast<const float4*>(x + i);
        const float4 b = *reinterpret_cast<const float4*>(x + i + 4);
        u16x8 h;
        h[0] = f2bf(a.x); h[1] = f2bf(a.y); h[2] = f2bf(a.z); h[3] = f2bf(a.w);
        h[4] = f2bf(b.x); h[5] = f2bf(b.y); h[6] = f2bf(b.z); h[7] = f2bf(b.w);
        *reinterpret_cast<u16x8*>(xb + i) = h;
    } else {                                // concat qkv bias
        const int i = (bid - 8448) * 256 + threadIdx.x;
        if (i < 2304)
            bqkv[i] = i < 768 ? bq[i] : (i < 1536 ? bk[i - 768] : bv[i - 1536]);
    }
}

// ---------------------------------------------------------------------------
// bf16 MFMA GEMM: C[Mr x N] = A[Mr x K] @ B[N x K]^T + bias
// 128x128 tile, BK=32, 4 waves, double-buffered LDS.
// EPI: 2 = gelu+bf16 out, 3 = QKV mode (QK bf16 [row][1536], V written
//      transposed to VT[b][h][d][tok], natural token order).
// ---------------------------------------------------------------------------
template<int EPI>
__global__ __launch_bounds__(256)
void gemm_bf16(const u16* __restrict__ A, const u16* __restrict__ B,
               const float* __restrict__ bias, void* __restrict__ Cp,
               u16* __restrict__ VTp, int K, int N)
{
    __shared__ u16 As[2][128 * 32];
    __shared__ u16 Bs[2][128 * 32];
    const int tid  = threadIdx.x;
    const int lane = tid & 63;
    const int w    = tid >> 6;
    const int m0 = blockIdx.x * 128, n0 = blockIdx.y * 128;
    const int wr = (w >> 1) << 6, wc = (w & 1) << 6;

    const int seg0 = (w << 11) + lane * 16;
    const int row0 = seg0 >> 6, cb0 = (seg0 & 63) >> 1;
    const int seg1 = seg0 + 1024;
    const int row1 = seg1 >> 6, cb1 = (seg1 & 63) >> 1;
    const u16* a0 = A + (size_t)(m0 + row0) * K + cb0;
    const u16* a1 = A + (size_t)(m0 + row1) * K + cb1;
    const u16* b0 = B + (size_t)(n0 + row0) * K + cb0;
    const u16* b1 = B + (size_t)(n0 + row1) * K + cb1;
    const int lo0 = (w * 2 + 0) << 9;
    const int lo1 = (w * 2 + 1) << 9;

    int aIdx[4], bIdx[4];
#pragma unroll
    for (int i = 0; i < 4; ++i) {
        aIdx[i] = (wr + i * 16 + (lane & 15)) * 32 + ((lane >> 4) << 3);
        bIdx[i] = (wc + i * 16 + (lane & 15)) * 32 + ((lane >> 4) << 3);
    }

    f32x4 acc[4][4];
#pragma unroll
    for (int i = 0; i < 4; ++i)
#pragma unroll
        for (int j = 0; j < 4; ++j)
#pragma unroll
            for (int q = 0; q < 4; ++q) acc[i][j][q] = 0.f;

    gload_lds16(a0, &As[0][lo0]);
    gload_lds16(a1, &As[0][lo1]);
    gload_lds16(b0, &Bs[0][lo0]);
    gload_lds16(b1, &Bs[0][lo1]);
    __syncthreads();

    int cur = 0;
    for (int k0 = 0; k0 < K; k0 += 32) {
        if (k0 + 32 < K) {
            gload_lds16(a0 + k0 + 32, &As[cur ^ 1][lo0]);
            gload_lds16(a1 + k0 + 32, &As[cur ^ 1][lo1]);
            gload_lds16(b0 + k0 + 32, &Bs[cur ^ 1][lo0]);
            gload_lds16(b1 + k0 + 32, &Bs[cur ^ 1][lo1]);
        }
        bf16x8 af[4], bv[4];
#pragma unroll
        for (int i = 0; i < 4; ++i)
            af[i] = *reinterpret_cast<const bf16x8*>(&As[cur][aIdx[i]]);
#pragma unroll
        for (int j = 0; j < 4; ++j)
            bv[j] = *reinterpret_cast<const bf16x8*>(&Bs[cur][bIdx[j]]);
#pragma unroll
        for (int i = 0; i < 4; ++i)
#pragma unroll
            for (int j = 0; j < 4; ++j)
                acc[i][j] = __builtin_amdgcn_mfma_f32_16x16x32_bf16(
                    af[i], bv[j], acc[i][j], 0, 0, 0);
        __syncthreads();
        cur ^= 1;
    }

#pragma unroll
    for (int i = 0; i < 4; ++i) {
#pragma unroll
        for (int q = 0; q < 4; ++q) {
            const int row = m0 + wr + i * 16 + ((lane >> 4) << 2) + q;
#pragma unroll
            for (int j = 0; j < 4; ++j) {
                const int col = n0 + wc + j * 16 + (lane & 15);
                float v = acc[i][j][q] + bias[col];
                if (EPI == 2) {
                    // gelu(tanh form) == v * sigmoid(2*0.79788456*(v+0.044715 v^3))
                    const float z = 1.5957691216057308f *
                                    (v + 0.044715f * v * v * v);
                    const float e = __builtin_amdgcn_exp2f(z * -1.4426950408889634f);
                    v = v * __builtin_amdgcn_rcpf(1.f + e);
                    ((u16*)Cp)[(size_t)row * N + col] = cvt_bf(v);
                } else {   // EPI == 3: QKV
                    if (n0 < 1536) {
                        ((u16*)Cp)[(size_t)row * 1536 + col] = cvt_bf(v);
                    } else {
                        const int c2 = col - 1536;
                        const int hh = c2 >> 6, dd = c2 & 63;
                        const int bb = row >> 11, tok = row & 2047;
                        VTp[((size_t)(bb * NHEAD + hh) * HDIM + dd) * SEQ + tok]
                            = cvt_bf(v);
                    }
                }
            }
        }
    }
}

// ---------------------------------------------------------------------------
// BM=64 x BN=128 split-K GEMM for N=768 shapes, fp32 out.
// grid.z = 2: z=0 computes K-half 0 (+bias) -> C0; z=1 K-half 1 -> C1.
// ---------------------------------------------------------------------------
__global__ __launch_bounds__(256)
void gemm_n64(const u16* __restrict__ A, const u16* __restrict__ B,
              const float* __restrict__ bias, float* __restrict__ C0,
              float* __restrict__ C1, int Khalf, int Ktot, int N)
{
    __shared__ u16 As[2][64 * 32];
    __shared__ u16 Bs[2][128 * 32];
    const int tid  = threadIdx.x;
    const int lane = tid & 63;
    const int w    = tid >> 6;
    const int l15  = lane & 15;
    const int g    = lane >> 4;
    const int m0 = blockIdx.x * 64, n0 = blockIdx.y * 128;
    const int zz = blockIdx.z;
    const int kbase = zz * Khalf;
    float* __restrict__ C = zz ? C1 : C0;

    const int segA = (w << 10) + lane * 16;
    const int rowA = segA >> 6, cbA = (segA & 63) >> 1;
    const u16* aP = A + (size_t)(m0 + rowA) * Ktot + kbase + cbA;
    const int loA = w << 9;
    const int seg0 = (w << 11) + lane * 16;
    const int row0 = seg0 >> 6, cb0 = (seg0 & 63) >> 1;
    const int seg1 = seg0 + 1024;
    const int row1 = seg1 >> 6, cb1 = (seg1 & 63) >> 1;
    const u16* b0 = B + (size_t)(n0 + row0) * Ktot + kbase + cb0;
    const u16* b1 = B + (size_t)(n0 + row1) * Ktot + kbase + cb1;
    const int lo0 = w << 10, lo1 = (w << 10) + 512;

    int aIdx[4], bIdx[2];
#pragma unroll
    for (int i = 0; i < 4; ++i) aIdx[i] = (i * 16 + l15) * 32 + (g << 3);
#pragma unroll
    for (int j = 0; j < 2; ++j) bIdx[j] = ((w << 5) + j * 16 + l15) * 32 + (g << 3);

    f32x4 acc[4][2];
#pragma unroll
    for (int i = 0; i < 4; ++i)
#pragma unroll
        for (int j = 0; j < 2; ++j)
#pragma unroll
            for (int q = 0; q < 4; ++q) acc[i][j][q] = 0.f;

    gload_lds16(aP, &As[0][loA]);
    gload_lds16(b0, &Bs[0][lo0]);
    gload_lds16(b1, &Bs[0][lo1]);
    __syncthreads();

    int cur = 0;
    for (int k0 = 0; k0 < Khalf; k0 += 32) {
        if (k0 + 32 < Khalf) {
            gload_lds16(aP + k0 + 32, &As[cur ^ 1][loA]);
            gload_lds16(b0 + k0 + 32, &Bs[cur ^ 1][lo0]);
            gload_lds16(b1 + k0 + 32, &Bs[cur ^ 1][lo1]);
        }
        bf16x8 af[4], bv[2];
#pragma unroll
        for (int i = 0; i < 4; ++i)
            af[i] = *reinterpret_cast<const bf16x8*>(&As[cur][aIdx[i]]);
#pragma unroll
        for (int j = 0; j < 2; ++j)
            bv[j] = *reinterpret_cast<const bf16x8*>(&Bs[cur][bIdx[j]]);
#pragma unroll
        for (int i = 0; i < 4; ++i)
#pragma unroll
            for (int j = 0; j < 2; ++j)
                acc[i][j] = __builtin_amdgcn_mfma_f32_16x16x32_bf16(
                    af[i], bv[j], acc[i][j], 0, 0, 0);
        __syncthreads();
        cur ^= 1;
    }

#pragma unroll
    for (int i = 0; i < 4; ++i) {
#pragma unroll
        for (int q = 0; q < 4; ++q) {
            const int row = m0 + i * 16 + (g << 2) + q;
#pragma unroll
            for (int j = 0; j < 2; ++j) {
                const int col = n0 + (w << 5) + j * 16 + l15;
                const float bb = zz ? 0.f : bias[col];
                C[(size_t)row * N + col] = acc[i][j][q] + bb;
            }
        }
    }
}

// ---------------------------------------------------------------------------
// MFMA flash attention, 32x32x16, swapped QK^T (S^T = K x Q^T), P IN REGS,
// staged via global_load_lds (zero staging VALU, r10 pattern):
// linear LDS dest + 16B-chunk XOR pre-swizzled GLOBAL source; reads apply
// the same XOR. 2-way conflicts per quarter-wave (free). PV B-frags are two
// ds_read_b64 at swizzle-consistent 8B granules. The S^T C-layout regs ARE
// the PV A-fragment via pi(hi*8+j)=(j&3)+8*(j>>2)+4*hi (r11-verified).
// Split-KV z=2 + attn_merge. Static-max softmax (exp2-domain, Q pre-scaled).
// ---------------------------------------------------------------------------
#define SM_SCALE 0.18033688011112042f   // log2(e)/8

__global__ __launch_bounds__(256)
void attn_mfma(const u16* __restrict__ QK, const u16* __restrict__ VT,
               u16* __restrict__ O0, u16* __restrict__ O1,
               float* __restrict__ Sp)
{
    __shared__ u16 Ks[2][64 * 64];   // [key][d], 16B chunks XOR-swizzled
    __shared__ u16 Vs[2][64 * 64];   // [d][key], 16B chunks XOR-swizzled

    const int tid  = threadIdx.x;
    const int lane = tid & 63;
    const int w    = tid >> 6;           // 0..3
    const int l31  = lane & 31;
    const int hi   = lane >> 5;          // 0..1
    const int bh   = blockIdx.x;
    const int b    = bh / NHEAD, h = bh % NHEAD;
    const int q0   = blockIdx.y * 128;
    const int z    = blockIdx.z;
    const int keybase = z * 1024;
    const int bS   = b * SEQ;

    // ---- Q B-fragments (eta+scale folded): lane q = w*32+l31 ----
    bf16x8 bq[4];
    {
        const u16* Qg = QK + (size_t)(bS + q0 + w * 32 + l31) * 1536 + h * HDIM;
#pragma unroll
        for (int s = 0; s < 4; ++s) {
            const u16x8 hq = *reinterpret_cast<const u16x8*>(
                Qg + s * 16 + hi * 8);
            const float sc = (s < 2) ? -SM_SCALE : SM_SCALE;  // d<32 <=> s<2
            u16x8 hs;
#pragma unroll
            for (int j = 0; j < 8; ++j)
                hs[j] = cvt_bf(bf2f(hq[j]) * sc);
            bq[s] = __builtin_bit_cast(bf16x8, hs);
        }
    }

    // ---- staging pointers (chunk-swizzled global src, linear LDS dst) ----
    const int rl = lane >> 3;                  // row-in-8
    const int cs = ((lane & 7) ^ rl) << 3;     // swizzled 16B chunk (u16)
    const u16* pK = QK + (size_t)(bS + keybase + 16 * w + rl) * 1536
                    + 768 + h * HDIM + cs;
    const u16* pV = VT + ((size_t)(b * NHEAD + h) * HDIM + 16 * w + rl) * SEQ
                    + keybase + cs;

    f32x16 accO[2];
#pragma unroll
    for (int dt = 0; dt < 2; ++dt)
#pragma unroll
        for (int r = 0; r < 16; ++r) accO[dt][r] = 0.f;
    float psum = 0.f;

#define ATTN_STAGE(c, kt)                                                   \
    do {                                                                    \
        u16* dK = &Ks[c][w * 1024];                                         \
        u16* dV = &Vs[c][w * 1024];                                         \
        gload_lds16(pK + (size_t)(kt) * 1536,       dK);                    \
        gload_lds16(pK + (size_t)((kt) + 8) * 1536, dK + 512);              \
        gload_lds16(pV + (kt),           dV);                               \
        gload_lds16(pV + (kt) + 8 * SEQ, dV + 512);                         \
    } while (0)

    ATTN_STAGE(0, 0);
    __syncthreads();
    int cur = 0;

    for (int kt = 0; kt < 1024; kt += 64) {
        if (kt + 64 < 1024) ATTN_STAGE(cur ^ 1, kt + 64);

        // ---- S^T = K x Q^T: A=K rows (keys), B=Q regs; C col = q = l31 ----
        f32x16 sac[2];
        __builtin_amdgcn_s_setprio(1);
#pragma unroll
        for (int t = 0; t < 2; ++t) {
#pragma unroll
            for (int r = 0; r < 16; ++r) sac[t][r] = 0.f;
            const int krow = (t * 32 + l31) * 64;
            const int m7 = l31 & 7;
#pragma unroll
            for (int s = 0; s < 4; ++s) {
                const bf16x8 ak = *reinterpret_cast<const bf16x8*>(
                    &Ks[cur][krow + (((s * 2 + hi) ^ m7) << 3)]);
                sac[t] = __builtin_amdgcn_mfma_f32_32x32x16_bf16(
                    ak, bq[s], sac[t], 0, 0, 0);
            }
        }
        __builtin_amdgcn_s_setprio(0);

        // ---- P = exp2(S') in registers; lane-local row sums ----
        u16x8 pk[4];
#pragma unroll
        for (int t = 0; t < 2; ++t)
#pragma unroll
            for (int r = 0; r < 16; ++r) {
                const float ev = __builtin_amdgcn_exp2f(sac[t][r]);
                psum += ev;
                pk[2 * t + (r >> 3)][r & 7] = cvt_bf(ev);
            }

        // ---- O += P @ V: A = P regs (pi-permuted), B = V from LDS ----
        __builtin_amdgcn_s_setprio(1);
#pragma unroll
        for (int t = 0; t < 2; ++t)
#pragma unroll
            for (int u = 0; u < 2; ++u) {
                const bf16x8 ap = __builtin_bit_cast(bf16x8, pk[2 * t + u]);
#pragma unroll
                for (int dt = 0; dt < 2; ++dt) {
                    const int d = dt * 32 + l31;
                    const int vrow = d * 64;
                    const int d7 = d & 7;
                    // global 8B granules 8t+4u+hi and 8t+4u+2+hi, swizzled:
                    const int g0 = 2 * ((4 * t + 2 * u)     ^ d7) + hi;
                    const int g1 = 2 * ((4 * t + 2 * u + 1) ^ d7) + hi;
                    const uint2 ra = *reinterpret_cast<const uint2*>(
                        &Vs[cur][vrow + 4 * g0]);
                    const uint2 rb = *reinterpret_cast<const uint2*>(
                        &Vs[cur][vrow + 4 * g1]);
                    const bf16x8 bv = __builtin_bit_cast(
                        bf16x8, make_uint4(ra.x, ra.y, rb.x, rb.y));
                    accO[dt] = __builtin_amdgcn_mfma_f32_32x32x16_bf16(
                        ap, bv, accO[dt], 0, 0, 0);
                }
            }
        __builtin_amdgcn_s_setprio(0);
        __syncthreads();
        cur ^= 1;
    }

    // ---- store unnormalized bf16 O-partial + f32 sum ----
    psum += __shfl_xor(psum, 32);
    u16* __restrict__ Oz = z ? O1 : O0;
#pragma unroll
    for (int dt = 0; dt < 2; ++dt)
#pragma unroll
        for (int r = 0; r < 16; ++r) {
            const int qr = q0 + w * 32 + (r & 3) + 8 * (r >> 2) + 4 * hi;
            Oz[(size_t)(bS + qr) * D_EMB + h * HDIM + dt * 32 + l31]
                = cvt_bf(accO[dt][r]);
        }
    if (lane < 32)
        Sp[(size_t)z * (BATCH * NHEAD * SEQ) + (b * NHEAD + h) * SEQ
           + q0 + w * 32 + l31] = psum;
#undef ATTN_STAGE
}

// ---------------------------------------------------------------------------
// Merge split-KV partials: Ab = (O0 + O1) / (S0 + S1), bf16 out.
// ---------------------------------------------------------------------------
__global__ __launch_bounds__(256)
void attn_merge(const u16* __restrict__ O0, const u16* __restrict__ O1,
                const float* __restrict__ Sp, u16* __restrict__ Ab)
{
    const int gid = blockIdx.x * 256 + threadIdx.x;   // ND/8 threads
    const size_t e = (size_t)gid * 8;
    const int row = gid / 96;            // 96 8-chunks per 768-row
    const int cc  = gid % 96;
    const int h   = cc >> 3;
    const int b   = row >> 11, q = row & 2047;
    const int si  = (b * NHEAD + h) * SEQ + q;
    const float s = Sp[si] + Sp[(size_t)(BATCH * NHEAD * SEQ) + si];
    const float inv = __builtin_amdgcn_rcpf(s);
    const u16x8 a = *reinterpret_cast<const u16x8*>(O0 + e);
    const u16x8 c = *reinterpret_cast<const u16x8*>(O1 + e);
    u16x8 o;
#pragma unroll
    for (int j = 0; j < 8; ++j)
        o[j] = cvt_bf((bf2f(a[j]) + bf2f(c[j])) * inv);
    *reinterpret_cast<u16x8*>(Ab + e) = o;
}

// ---------------------------------------------------------------------------
// Minkowski LN over 384/384 split with TWO residual inputs:
// Out = LN(X + R1 + R2) * g + b.
// XBF: X input is bf16. WF32: write fp32 Out. OutB optional bf16 out.
// ---------------------------------------------------------------------------
template<int XBF, int WF32>
__global__ __launch_bounds__(256)
void mink_ln(const void* __restrict__ Xp, const float* __restrict__ R1,
             const float* __restrict__ R2,
             const float* __restrict__ gt, const float* __restrict__ bt,
             const float* __restrict__ gs, const float* __restrict__ bs,
             float* __restrict__ Out, u16* __restrict__ OutB, int nrows)
{
    const int wid  = (int)((blockIdx.x * 256 + threadIdx.x) >> 6);
    const int lane = threadIdx.x & 63;
    const int row  = wid >> 1, half = wid & 1;
    if (row >= nrows) return;

    const float* g  = half ? gs : gt;
    const float* bb = half ? bs : bt;
    const size_t base = (size_t)row * D_EMB + half * 384;

    float v[6];
    float sum = 0.f;
#pragma unroll
    for (int i = 0; i < 6; ++i) {
        const size_t e = base + i * 64 + lane;
        const float xv = XBF ? bf2f(((const u16*)Xp)[e]) : ((const float*)Xp)[e];
        const float t = xv + R1[e] + R2[e];
        v[i] = t; sum += t;
    }
#pragma unroll
    for (int off = 32; off; off >>= 1) sum += __shfl_xor(sum, off);
    const float mean = sum * (1.f / 384.f);

    float ss = 0.f;
#pragma unroll
    for (int i = 0; i < 6; ++i) { const float d = v[i] - mean; ss += d * d; }
#pragma unroll
    for (int off = 32; off; off >>= 1) ss += __shfl_xor(ss, off);
    const float rstd = rsqrtf(ss * (1.f / 384.f) + 1e-5f);

#pragma unroll
    for (int i = 0; i < 6; ++i) {
        const int e = i * 64 + lane;
        const float o = (v[i] - mean) * rstd * g[e] + bb[e];
        if (WF32) Out[base + e] = o;
        if (OutB) OutB[base + e] = cvt_bf(o);
    }
}

// ---------------------------------------------------------------------------
extern "C" void kernel_launch(void* const* d_in, const int* in_sizes, int n_in,
                              void* d_out, int out_size, void* d_ws, size_t ws_size,
                              hipStream_t stream)
{
    const float* x   = (const float*)d_in[0];
    const float* Wq  = (const float*)d_in[1];
    const float* bq  = (const float*)d_in[2];
    const float* Wk  = (const float*)d_in[3];
    const float* bk  = (const float*)d_in[4];
    const float* Wv  = (const float*)d_in[5];
    const float* bv  = (const float*)d_in[6];
    const float* Wo  = (const float*)d_in[7];
    const float* bo  = (const float*)d_in[8];
    const float* g1t = (const float*)d_in[9];
    const float* b1t = (const float*)d_in[10];
    const float* g1s = (const float*)d_in[11];
    const float* b1s = (const float*)d_in[12];
    const float* W1  = (const float*)d_in[13];
    const float* bb1 = (const float*)d_in[14];
    const float* W2  = (const float*)d_in[15];
    const float* bb2 = (const float*)d_in[16];
    const float* g2t = (const float*)d_in[17];
    const float* b2t = (const float*)d_in[18];
    const float* g2s = (const float*)d_in[19];
    const float* b2s = (const float*)d_in[20];
    float* out = (float*)d_out;

    const size_t ND = (size_t)NROW * D_EMB;   // 3,145,728
    u16* WqkvoT = (u16*)d_ws;                 // [3072][768] rows q,k,v,o
    u16* W1T = WqkvoT + 2359296;              // [3072][768]
    u16* W2T = W1T + 2359296;                 // [768][3072]
    u16* xb  = W2T + 2359296;                 // ND (x bf16, then X1 bf16)
    u16* QKb = xb + ND;                       // [4096][1536] q|k
    u16* VTb = QKb + (size_t)NROW * 1536;     // [2][12][64][2048] natural
    u16* Ab  = VTb + ND;                      // ND (attn out bf16)
    u16* Hb  = QKb;                           // [4096][3072] over QKb+VTb+Ab
    float* QKf  = (float*)QKb;                // Wo split-K partial#2 (QK dead)
    float* AoF  = (float*)(Ab + ND);          // ND fp32 (Wo p1, then W2 p1)
    float* bqkv = AoF;                        // 2304 f32, dead before attn
    u16* Op0 = (u16*)AoF;                     // attn O-partials overlay AoF
    u16* Op1 = Op0 + ND;
    float* Sp = (float*)xb;                   // sums: xb content dead post-QKV

    const dim3 blk(256);

    prep<<<8457, blk, 0, stream>>>(Wq, Wk, Wv, Wo, W1, W2, bq, bk, bv, x,
                                   WqkvoT, W1T, W2T, xb, bqkv);

    // fused QKV projection (writes QKb + transposed V, natural order)
    gemm_bf16<3><<<dim3(32, 18), blk, 0, stream>>>(xb, WqkvoT, bqkv, QKb, VTb,
                                                   768, 2304);
    // split-KV attention + merge
    attn_mfma<<<dim3(BATCH * NHEAD, SEQ / 128, 2), blk, 0, stream>>>(
        QKb, VTb, Op0, Op1, Sp);
    attn_merge<<<(int)(ND / 8 / 256), blk, 0, stream>>>(Op0, Op1, Sp, Ab);

    // Wo projection, split-K=2: p1 -> AoF (+bias), p2 -> QKf (QK region dead)
    gemm_n64<<<dim3(64, 6, 2), blk, 0, stream>>>(
        Ab, WqkvoT + (size_t)2304 * 768, bo, AoF, QKf, 384, 768, 768);
    // LN1: X1 (bf16 only) -> xb
    mink_ln<0, 0><<<2048, blk, 0, stream>>>(x, AoF, QKf, g1t, b1t, g1s, b1s,
                                            nullptr, xb, NROW);
    gemm_bf16<2><<<dim3(32, 24), blk, 0, stream>>>(xb, W1T, bb1, Hb, nullptr,
                                                   768, 3072);
    // W2, split-K=2: p1 -> AoF (+bias), p2 -> out (overwritten by LN2 after read)
    gemm_n64<<<dim3(64, 6, 2), blk, 0, stream>>>(
        Hb, W2T, bb2, AoF, out, 1536, 3072, 768);
    mink_ln<1, 1><<<2048, blk, 0, stream>>>(xb, AoF, out, g2t, b2t, g2s, b2s,
                                            out, nullptr, NROW);
}

// Round 13
// 177.622 us; speedup vs baseline: 1.0851x; 1.0332x over previous
//
#include <hip/hip_runtime.h>
#include <cstddef>
#include <cstdint>

#define D_EMB  768
#define NHEAD  12
#define HDIM   64
#define THEAD  32
#define SEQ    2048
#define BATCH  2
#define NROW   (BATCH*SEQ)   // 4096
#define HID4   3072

typedef unsigned short u16;
typedef __bf16 bf16x8 __attribute__((ext_vector_type(8)));
typedef float  f32x4  __attribute__((ext_vector_type(4)));
typedef unsigned short u16x8 __attribute__((ext_vector_type(8)));

__device__ __forceinline__ u16 f2bf(float f) {
    unsigned u = __builtin_bit_cast(unsigned, f);
    return (u16)((u + 0x7FFFu + ((u >> 16) & 1u)) >> 16);
}
__device__ __forceinline__ float bf2f(u16 h) {
    return __builtin_bit_cast(float, (unsigned)h << 16);
}
__device__ __forceinline__ u16 cvt_bf(float f) {
    return __builtin_bit_cast(u16, (__bf16)f);
}

// global -> LDS direct copy, 16B per lane. LDS dst is wave-uniform base;
// HW writes base + lane*16. Global src is per-lane.
__device__ __forceinline__ void gload_lds16(const void* g, void* l) {
    __builtin_amdgcn_global_load_lds(
        reinterpret_cast<const __attribute__((address_space(1))) void*>(
            reinterpret_cast<uintptr_t>(g)),
        reinterpret_cast<__attribute__((address_space(3))) void*>(
            (uint32_t)reinterpret_cast<uintptr_t>(l)),
        16, 0, 0);
}

// ---------------------------------------------------------------------------
// Fused prep: all weight transposes + x cast + bias concat in one launch.
// ---------------------------------------------------------------------------
__device__ __forceinline__ void tcast(float (*t)[33], const float* __restrict__ W,
                                      u16* __restrict__ WT, int K, int M,
                                      int mt, int kt)
{
    const int m0 = mt * 32, k0 = kt * 32;
    const int tx = threadIdx.x & 31, ty = threadIdx.x >> 5;
#pragma unroll
    for (int i = 0; i < 32; i += 8)
        t[ty + i][tx] = W[(size_t)(k0 + ty + i) * M + m0 + tx];
    __syncthreads();
#pragma unroll
    for (int i = 0; i < 32; i += 8)
        WT[(size_t)(m0 + ty + i) * K + k0 + tx] = f2bf(t[tx][ty + i]);
}

__global__ __launch_bounds__(256)
void prep(const float* __restrict__ Wq, const float* __restrict__ Wk,
          const float* __restrict__ Wv, const float* __restrict__ Wo,
          const float* __restrict__ W1, const float* __restrict__ W2,
          const float* __restrict__ bq, const float* __restrict__ bk,
          const float* __restrict__ bv, const float* __restrict__ x,
          u16* __restrict__ WqkvoT, u16* __restrict__ W1T,
          u16* __restrict__ W2T, u16* __restrict__ xb,
          float* __restrict__ bqkv)
{
    __shared__ float t[32][33];
    const int bid = blockIdx.x;
    if (bid < 2304) {                       // Wq/Wk/Wv/Wo 768x768 -> [z*768+m][k]
        const int z = bid / 576, r = bid % 576;
        const float* W = z == 0 ? Wq : z == 1 ? Wk : z == 2 ? Wv : Wo;
        tcast(t, W, WqkvoT + (size_t)z * 768 * 768, 768, 768, r % 24, r / 24);
    } else if (bid < 4608) {                // W1 [768][3072] -> [3072][768]
        const int r = bid - 2304;
        tcast(t, W1, W1T, 768, 3072, r % 96, r / 96);
    } else if (bid < 6912) {                // W2 [3072][768] -> [768][3072]
        const int r = bid - 4608;
        tcast(t, W2, W2T, 3072, 768, r % 24, r / 24);
    } else if (bid < 8448) {                // cast x -> bf16
        const int i = (bid - 6912) * 2048 + threadIdx.x * 8;
        const float4 a = *reinterpret_cast<const float4*>(x + i);
        const float4 b = *reinterpret_cast<const float4*>(x + i + 4);
        u16x8 h;
        h[0] = f2bf(a.x); h[1] = f2bf(a.y); h[2] = f2bf(a.z); h[3] = f2bf(a.w);
        h[4] = f2bf(b.x); h[5] = f2bf(b.y); h[6] = f2bf(b.z); h[7] = f2bf(b.w);
        *reinterpret_cast<u16x8*>(xb + i) = h;
    } else {                                // concat qkv bias
        const int i = (bid - 8448) * 256 + threadIdx.x;
        if (i < 2304)
            bqkv[i] = i < 768 ? bq[i] : (i < 1536 ? bk[i - 768] : bv[i - 1536]);
    }
}

// ---------------------------------------------------------------------------
// bf16 MFMA GEMM: C[Mr x N] = A[Mr x K] @ B[N x K]^T + bias
// 128x128 tile, BK=32, 4 waves, double-buffered LDS.
// EPI: 2 = gelu+bf16 out, 3 = QKV mode (QK bf16 [row][1536], V written
//      transposed AND token-permuted to VT[b][h][d][kt + p(tok)]).
// ---------------------------------------------------------------------------
template<int EPI>
__global__ __launch_bounds__(256)
void gemm_bf16(const u16* __restrict__ A, const u16* __restrict__ B,
               const float* __restrict__ bias, void* __restrict__ Cp,
               u16* __restrict__ VTp, int K, int N)
{
    __shared__ u16 As[2][128 * 32];
    __shared__ u16 Bs[2][128 * 32];
    const int tid  = threadIdx.x;
    const int lane = tid & 63;
    const int w    = tid >> 6;
    const int m0 = blockIdx.x * 128, n0 = blockIdx.y * 128;
    const int wr = (w >> 1) << 6, wc = (w & 1) << 6;

    const int seg0 = (w << 11) + lane * 16;
    const int row0 = seg0 >> 6, cb0 = (seg0 & 63) >> 1;
    const int seg1 = seg0 + 1024;
    const int row1 = seg1 >> 6, cb1 = (seg1 & 63) >> 1;
    const u16* a0 = A + (size_t)(m0 + row0) * K + cb0;
    const u16* a1 = A + (size_t)(m0 + row1) * K + cb1;
    const u16* b0 = B + (size_t)(n0 + row0) * K + cb0;
    const u16* b1 = B + (size_t)(n0 + row1) * K + cb1;
    const int lo0 = (w * 2 + 0) << 9;
    const int lo1 = (w * 2 + 1) << 9;

    int aIdx[4], bIdx[4];
#pragma unroll
    for (int i = 0; i < 4; ++i) {
        aIdx[i] = (wr + i * 16 + (lane & 15)) * 32 + ((lane >> 4) << 3);
        bIdx[i] = (wc + i * 16 + (lane & 15)) * 32 + ((lane >> 4) << 3);
    }

    f32x4 acc[4][4];
#pragma unroll
    for (int i = 0; i < 4; ++i)
#pragma unroll
        for (int j = 0; j < 4; ++j)
#pragma unroll
            for (int q = 0; q < 4; ++q) acc[i][j][q] = 0.f;

    gload_lds16(a0, &As[0][lo0]);
    gload_lds16(a1, &As[0][lo1]);
    gload_lds16(b0, &Bs[0][lo0]);
    gload_lds16(b1, &Bs[0][lo1]);
    __syncthreads();

    int cur = 0;
    for (int k0 = 0; k0 < K; k0 += 32) {
        if (k0 + 32 < K) {
            gload_lds16(a0 + k0 + 32, &As[cur ^ 1][lo0]);
            gload_lds16(a1 + k0 + 32, &As[cur ^ 1][lo1]);
            gload_lds16(b0 + k0 + 32, &Bs[cur ^ 1][lo0]);
            gload_lds16(b1 + k0 + 32, &Bs[cur ^ 1][lo1]);
        }
        bf16x8 af[4], bv[4];
#pragma unroll
        for (int i = 0; i < 4; ++i)
            af[i] = *reinterpret_cast<const bf16x8*>(&As[cur][aIdx[i]]);
#pragma unroll
        for (int j = 0; j < 4; ++j)
            bv[j] = *reinterpret_cast<const bf16x8*>(&Bs[cur][bIdx[j]]);
#pragma unroll
        for (int i = 0; i < 4; ++i)
#pragma unroll
            for (int j = 0; j < 4; ++j)
                acc[i][j] = __builtin_amdgcn_mfma_f32_16x16x32_bf16(
                    af[i], bv[j], acc[i][j], 0, 0, 0);
        __syncthreads();
        cur ^= 1;
    }

#pragma unroll
    for (int i = 0; i < 4; ++i) {
#pragma unroll
        for (int q = 0; q < 4; ++q) {
            const int row = m0 + wr + i * 16 + ((lane >> 4) << 2) + q;
#pragma unroll
            for (int j = 0; j < 4; ++j) {
                const int col = n0 + wc + j * 16 + (lane & 15);
                float v = acc[i][j][q] + bias[col];
                if (EPI == 2) {
                    // gelu(tanh form) == v * sigmoid(2*0.79788456*(v+0.044715 v^3))
                    const float z = 1.5957691216057308f *
                                    (v + 0.044715f * v * v * v);
                    const float e = __builtin_amdgcn_exp2f(z * -1.4426950408889634f);
                    v = v * __builtin_amdgcn_rcpf(1.f + e);
                    ((u16*)Cp)[(size_t)row * N + col] = cvt_bf(v);
                } else {   // EPI == 3: QKV
                    if (n0 < 1536) {
                        ((u16*)Cp)[(size_t)row * 1536 + col] = cvt_bf(v);
                    } else {
                        const int c2 = col - 1536;
                        const int hh = c2 >> 6, dd = c2 & 63;
                        const int bb = row >> 11, tok = row & 2047;
                        const int t = tok & 63;
                        const int p = ((t & 15) << 2) | (t >> 4);
                        VTp[((size_t)(bb * NHEAD + hh) * HDIM + dd) * SEQ
                            + (tok & ~63) + p] = cvt_bf(v);
                    }
                }
            }
        }
    }
}

// ---------------------------------------------------------------------------
// BM=64 x BN=128 split-K GEMM for N=768 shapes, bf16 partial outputs.
// grid.z = 2: z=0 computes K-half 0 (+bias) -> C0; z=1 K-half 1 -> C1.
// Consumer (mink_ln) adds bf2f(C0) + bf2f(C1).
// ---------------------------------------------------------------------------
__global__ __launch_bounds__(256)
void gemm_n64(const u16* __restrict__ A, const u16* __restrict__ B,
              const float* __restrict__ bias, u16* __restrict__ C0,
              u16* __restrict__ C1, int Khalf, int Ktot, int N)
{
    __shared__ u16 As[2][64 * 32];
    __shared__ u16 Bs[2][128 * 32];
    const int tid  = threadIdx.x;
    const int lane = tid & 63;
    const int w    = tid >> 6;
    const int l15  = lane & 15;
    const int g    = lane >> 4;
    const int m0 = blockIdx.x * 64, n0 = blockIdx.y * 128;
    const int zz = blockIdx.z;
    const int kbase = zz * Khalf;
    u16* __restrict__ C = zz ? C1 : C0;

    const int segA = (w << 10) + lane * 16;
    const int rowA = segA >> 6, cbA = (segA & 63) >> 1;
    const u16* aP = A + (size_t)(m0 + rowA) * Ktot + kbase + cbA;
    const int loA = w << 9;
    const int seg0 = (w << 11) + lane * 16;
    const int row0 = seg0 >> 6, cb0 = (seg0 & 63) >> 1;
    const int seg1 = seg0 + 1024;
    const int row1 = seg1 >> 6, cb1 = (seg1 & 63) >> 1;
    const u16* b0 = B + (size_t)(n0 + row0) * Ktot + kbase + cb0;
    const u16* b1 = B + (size_t)(n0 + row1) * Ktot + kbase + cb1;
    const int lo0 = w << 10, lo1 = (w << 10) + 512;

    int aIdx[4], bIdx[2];
#pragma unroll
    for (int i = 0; i < 4; ++i) aIdx[i] = (i * 16 + l15) * 32 + (g << 3);
#pragma unroll
    for (int j = 0; j < 2; ++j) bIdx[j] = ((w << 5) + j * 16 + l15) * 32 + (g << 3);

    f32x4 acc[4][2];
#pragma unroll
    for (int i = 0; i < 4; ++i)
#pragma unroll
        for (int j = 0; j < 2; ++j)
#pragma unroll
            for (int q = 0; q < 4; ++q) acc[i][j][q] = 0.f;

    gload_lds16(aP, &As[0][loA]);
    gload_lds16(b0, &Bs[0][lo0]);
    gload_lds16(b1, &Bs[0][lo1]);
    __syncthreads();

    int cur = 0;
    for (int k0 = 0; k0 < Khalf; k0 += 32) {
        if (k0 + 32 < Khalf) {
            gload_lds16(aP + k0 + 32, &As[cur ^ 1][loA]);
            gload_lds16(b0 + k0 + 32, &Bs[cur ^ 1][lo0]);
            gload_lds16(b1 + k0 + 32, &Bs[cur ^ 1][lo1]);
        }
        bf16x8 af[4], bv[2];
#pragma unroll
        for (int i = 0; i < 4; ++i)
            af[i] = *reinterpret_cast<const bf16x8*>(&As[cur][aIdx[i]]);
#pragma unroll
        for (int j = 0; j < 2; ++j)
            bv[j] = *reinterpret_cast<const bf16x8*>(&Bs[cur][bIdx[j]]);
#pragma unroll
        for (int i = 0; i < 4; ++i)
#pragma unroll
            for (int j = 0; j < 2; ++j)
                acc[i][j] = __builtin_amdgcn_mfma_f32_16x16x32_bf16(
                    af[i], bv[j], acc[i][j], 0, 0, 0);
        __syncthreads();
        cur ^= 1;
    }

#pragma unroll
    for (int i = 0; i < 4; ++i) {
#pragma unroll
        for (int q = 0; q < 4; ++q) {
            const int row = m0 + i * 16 + (g << 2) + q;
#pragma unroll
            for (int j = 0; j < 2; ++j) {
                const int col = n0 + (w << 5) + j * 16 + l15;
                const float bb = zz ? 0.f : bias[col];
                C[(size_t)row * N + col] = cvt_bf(acc[i][j][q] + bb);
            }
        }
    }
}

// ---------------------------------------------------------------------------
// MFMA flash attention (r9 config: 4 waves x 16 q-rows, 768 blocks, dbuf,
// VALU-lean softmax: pre-scaled Q, exp2, ones-fragment row sums, setprio).
// ---------------------------------------------------------------------------
#define SM_SCALE 0.18033688011112042f   // log2(e)/8

__global__ __launch_bounds__(256)
void attn_mfma(const u16* __restrict__ QK, const u16* __restrict__ VT,
               u16* __restrict__ O)
{
    __shared__ u16 Ks[2][64 * 64];
    __shared__ u16 Vs[2][64 * 64];
    __shared__ u16 Ps[64 * 72];   // stride 72 u16 = 144B

    const int tid  = threadIdx.x;
    const int lane = tid & 63;
    const int w    = tid >> 6;           // 0..3
    const int l15  = lane & 15;
    const int g    = lane >> 4;
    const int bh   = blockIdx.x;
    const int b    = bh / NHEAD, h = bh % NHEAD;
    const int q0   = blockIdx.y * 64;
    const int bS   = b * SEQ;

    // ---- Q A-fragments, pre-scaled by +-SM_SCALE (eta: kk==0 negative) ----
    bf16x8 aq[2];
    {
        const u16* Qg = QK + (size_t)(bS + q0 + (w << 4) + l15) * 1536 + h * HDIM;
#pragma unroll
        for (int kk = 0; kk < 2; ++kk) {
            const u16x8 hq = *reinterpret_cast<const u16x8*>(Qg + kk * 32 + g * 8);
            const float sc = (kk == 0) ? -SM_SCALE : SM_SCALE;
            u16x8 hs;
#pragma unroll
            for (int j = 0; j < 8; ++j)
                hs[j] = cvt_bf(bf2f(hq[j]) * sc);
            aq[kk] = __builtin_bit_cast(bf16x8, hs);
        }
    }

    // ---- staging pointers (chunk-swizzled global src, linear LDS dst) ----
    const int rl = lane >> 3;
    const int cs = ((lane & 7) ^ rl) << 3;
    const u16* pK = QK + (size_t)(bS + 16 * w + rl) * 1536 + 768 + h * HDIM + cs;
    const u16* pV = VT + ((size_t)(b * NHEAD + h) * HDIM + 16 * w + rl) * SEQ + cs;

    int swz[2];
#pragma unroll
    for (int kk = 0; kk < 2; ++kk)
        swz[kk] = ((kk * 4 + g) ^ (l15 & 7)) << 3;

    bf16x8 vones;
    {
        u16x8 o16;
#pragma unroll
        for (int j = 0; j < 8; ++j) o16[j] = 0x3F80u;
        vones = __builtin_bit_cast(bf16x8, o16);
    }

    f32x4 accO[4];
#pragma unroll
    for (int n = 0; n < 4; ++n)
#pragma unroll
        for (int q = 0; q < 4; ++q) accO[n][q] = 0.f;
    f32x4 accS;
#pragma unroll
    for (int q = 0; q < 4; ++q) accS[q] = 0.f;

#define ATTN_STAGE(c, kt)                                                   \
    do {                                                                    \
        u16* dK = &Ks[c][w * 1024];                                         \
        u16* dV = &Vs[c][w * 1024];                                         \
        gload_lds16(pK + (size_t)(kt) * 1536,       dK);                    \
        gload_lds16(pK + (size_t)((kt) + 8) * 1536, dK + 512);              \
        gload_lds16(pV + (kt),           dV);                               \
        gload_lds16(pV + (kt) + 8 * SEQ, dV + 512);                         \
    } while (0)

    ATTN_STAGE(0, 0);
    __syncthreads();
    int cur = 0;

    for (int kt = 0; kt < SEQ; kt += 64) {
        if (kt + 64 < SEQ) ATTN_STAGE(cur ^ 1, kt + 64);

        f32x4 sac[4];
        __builtin_amdgcn_s_setprio(1);
#pragma unroll
        for (int n = 0; n < 4; ++n) {
#pragma unroll
            for (int q = 0; q < 4; ++q) sac[n][q] = 0.f;
#pragma unroll
            for (int kk = 0; kk < 2; ++kk) {
                const bf16x8 bk = *reinterpret_cast<const bf16x8*>(
                    &Ks[cur][(n * 16 + l15) * 64 + swz[kk]]);
                sac[n] = __builtin_amdgcn_mfma_f32_16x16x32_bf16(
                    aq[kk], bk, sac[n], 0, 0, 0);
            }
        }
        __builtin_amdgcn_s_setprio(0);

#pragma unroll
        for (int r4 = 0; r4 < 4; ++r4) {
            const int prow = (w << 4) + (g << 2) + r4;
            const float sv0 = __builtin_amdgcn_exp2f(sac[0][r4]);
            const float sv1 = __builtin_amdgcn_exp2f(sac[1][r4]);
            const float sv2 = __builtin_amdgcn_exp2f(sac[2][r4]);
            const float sv3 = __builtin_amdgcn_exp2f(sac[3][r4]);
            ushort4 pk4;
            pk4.x = cvt_bf(sv0);
            pk4.y = cvt_bf(sv1);
            pk4.z = cvt_bf(sv2);
            pk4.w = cvt_bf(sv3);
            *reinterpret_cast<ushort4*>(&Ps[prow * 72 + (l15 << 2)]) = pk4;
        }

        bf16x8 pa[2];
#pragma unroll
        for (int kk = 0; kk < 2; ++kk)
            pa[kk] = *reinterpret_cast<const bf16x8*>(
                &Ps[((w << 4) + l15) * 72 + kk * 32 + g * 8]);
        __builtin_amdgcn_s_setprio(1);
#pragma unroll
        for (int n = 0; n < 4; ++n) {
#pragma unroll
            for (int kk = 0; kk < 2; ++kk) {
                const bf16x8 bv = *reinterpret_cast<const bf16x8*>(
                    &Vs[cur][(n * 16 + l15) * 64 + swz[kk]]);
                accO[n] = __builtin_amdgcn_mfma_f32_16x16x32_bf16(
                    pa[kk], bv, accO[n], 0, 0, 0);
            }
        }
#pragma unroll
        for (int kk = 0; kk < 2; ++kk)
            accS = __builtin_amdgcn_mfma_f32_16x16x32_bf16(
                pa[kk], vones, accS, 0, 0, 0);
        __builtin_amdgcn_s_setprio(0);
        __syncthreads();
        cur ^= 1;
    }

#pragma unroll
    for (int r4 = 0; r4 < 4; ++r4) {
        const float inv = 1.f / accS[r4];
        const int qr = q0 + (w << 4) + (g << 2) + r4;
#pragma unroll
        for (int n = 0; n < 4; ++n)
            O[(size_t)(bS + qr) * D_EMB + h * HDIM + n * 16 + l15]
                = cvt_bf(accO[n][r4] * inv);
    }
#undef ATTN_STAGE
}

// ---------------------------------------------------------------------------
// Minkowski LN over 384/384 split with TWO bf16 residual inputs:
// Out = LN(X + R1 + R2) * g + b. 2-wide vectorized accesses.
// XBF: X input is bf16. Out (fp32) / OutB (bf16) optional.
// ---------------------------------------------------------------------------
template<int XBF>
__global__ __launch_bounds__(256)
void mink_ln(const void* __restrict__ Xp, const u16* __restrict__ R1,
             const u16* __restrict__ R2,
             const float* __restrict__ gt, const float* __restrict__ bt,
             const float* __restrict__ gs, const float* __restrict__ bs,
             float* __restrict__ Out, u16* __restrict__ OutB, int nrows)
{
    const int wid  = (int)((blockIdx.x * 256 + threadIdx.x) >> 6);
    const int lane = threadIdx.x & 63;
    const int row  = wid >> 1, half = wid & 1;
    if (row >= nrows) return;

    const float* g  = half ? gs : gt;
    const float* bb = half ? bs : bt;
    const size_t base = (size_t)row * D_EMB + half * 384;

    float v[6];
    float sum = 0.f;
#pragma unroll
    for (int i = 0; i < 3; ++i) {
        const size_t e = base + i * 128 + lane * 2;
        float x0, x1;
        if (XBF) {
            const unsigned xv = *reinterpret_cast<const unsigned*>(
                (const u16*)Xp + e);
            x0 = bf2f((u16)xv); x1 = bf2f((u16)(xv >> 16));
        } else {
            const float2 xf = *reinterpret_cast<const float2*>(
                (const float*)Xp + e);
            x0 = xf.x; x1 = xf.y;
        }
        const unsigned r1 = *reinterpret_cast<const unsigned*>(R1 + e);
        const unsigned r2 = *reinterpret_cast<const unsigned*>(R2 + e);
        const float t0 = x0 + bf2f((u16)r1) + bf2f((u16)r2);
        const float t1 = x1 + bf2f((u16)(r1 >> 16)) + bf2f((u16)(r2 >> 16));
        v[2 * i] = t0; v[2 * i + 1] = t1;
        sum += t0 + t1;
    }
#pragma unroll
    for (int off = 32; off; off >>= 1) sum += __shfl_xor(sum, off);
    const float mean = sum * (1.f / 384.f);

    float ss = 0.f;
#pragma unroll
    for (int i = 0; i < 6; ++i) { const float d = v[i] - mean; ss += d * d; }
#pragma unroll
    for (int off = 32; off; off >>= 1) ss += __shfl_xor(ss, off);
    const float rstd = rsqrtf(ss * (1.f / 384.f) + 1e-5f);

#pragma unroll
    for (int i = 0; i < 3; ++i) {
        const int e = i * 128 + lane * 2;
        const float o0 = (v[2 * i]     - mean) * rstd * g[e]     + bb[e];
        const float o1 = (v[2 * i + 1] - mean) * rstd * g[e + 1] + bb[e + 1];
        if (Out) {
            float2 of; of.x = o0; of.y = o1;
            *reinterpret_cast<float2*>(Out + base + e) = of;
        }
        if (OutB) {
            const unsigned pk = (unsigned)cvt_bf(o0) |
                                ((unsigned)cvt_bf(o1) << 16);
            *reinterpret_cast<unsigned*>(OutB + base + e) = pk;
        }
    }
}

// ---------------------------------------------------------------------------
extern "C" void kernel_launch(void* const* d_in, const int* in_sizes, int n_in,
                              void* d_out, int out_size, void* d_ws, size_t ws_size,
                              hipStream_t stream)
{
    const float* x   = (const float*)d_in[0];
    const float* Wq  = (const float*)d_in[1];
    const float* bq  = (const float*)d_in[2];
    const float* Wk  = (const float*)d_in[3];
    const float* bk  = (const float*)d_in[4];
    const float* Wv  = (const float*)d_in[5];
    const float* bv  = (const float*)d_in[6];
    const float* Wo  = (const float*)d_in[7];
    const float* bo  = (const float*)d_in[8];
    const float* g1t = (const float*)d_in[9];
    const float* b1t = (const float*)d_in[10];
    const float* g1s = (const float*)d_in[11];
    const float* b1s = (const float*)d_in[12];
    const float* W1  = (const float*)d_in[13];
    const float* bb1 = (const float*)d_in[14];
    const float* W2  = (const float*)d_in[15];
    const float* bb2 = (const float*)d_in[16];
    const float* g2t = (const float*)d_in[17];
    const float* b2t = (const float*)d_in[18];
    const float* g2s = (const float*)d_in[19];
    const float* b2s = (const float*)d_in[20];
    float* out = (float*)d_out;

    const size_t ND = (size_t)NROW * D_EMB;   // 3,145,728
    u16* WqkvoT = (u16*)d_ws;                 // [3072][768] rows q,k,v,o
    u16* W1T = WqkvoT + 2359296;              // [3072][768]
    u16* W2T = W1T + 2359296;                 // [768][3072]
    u16* xb  = W2T + 2359296;                 // ND (x bf16, then X1 bf16)
    u16* QKb = xb + ND;                       // [4096][1536] q|k
    u16* VTb = QKb + (size_t)NROW * 1536;     // [2][12][64][2048] (tok-permuted)
    u16* Ab  = VTb + ND;                      // ND (attn out bf16)
    u16* Hb  = QKb;                           // [4096][3072] over QKb+VTb+Ab
    float* bqkv = (float*)(Ab + ND);          // 2304 f32, dead before Wo gemm
    u16* AoFb = (u16*)(Ab + ND);              // bf16 partial#1 (Wo, then W2)
    u16* QKfb = (u16*)QKb;                    // Wo partial#2 (QK dead post-attn)
    u16* X2b  = (u16*)((float*)(Ab + ND) + ND); // W2 partial#2 (old X1 slot)

    const dim3 blk(256);

    prep<<<8457, blk, 0, stream>>>(Wq, Wk, Wv, Wo, W1, W2, bq, bk, bv, x,
                                   WqkvoT, W1T, W2T, xb, bqkv);

    // fused QKV projection (writes QKb + transposed, token-permuted V)
    gemm_bf16<3><<<dim3(32, 18), blk, 0, stream>>>(xb, WqkvoT, bqkv, QKb, VTb,
                                                   768, 2304);
    attn_mfma<<<dim3(BATCH * NHEAD, SEQ / 64), blk, 0, stream>>>(QKb, VTb, Ab);

    // Wo projection, split-K=2, bf16 partials: p1 -> AoFb (+bias), p2 -> QKfb
    gemm_n64<<<dim3(64, 6, 2), blk, 0, stream>>>(
        Ab, WqkvoT + (size_t)2304 * 768, bo, AoFb, QKfb, 384, 768, 768);
    // LN1: X1 (bf16 only) -> xb
    mink_ln<0><<<2048, blk, 0, stream>>>(x, AoFb, QKfb, g1t, b1t, g1s, b1s,
                                         nullptr, xb, NROW);
    gemm_bf16<2><<<dim3(32, 24), blk, 0, stream>>>(xb, W1T, bb1, Hb, nullptr,
                                                   768, 3072);
    // W2, split-K=2, bf16 partials: p1 -> AoFb (+bias), p2 -> X2b
    gemm_n64<<<dim3(64, 6, 2), blk, 0, stream>>>(
        Hb, W2T, bb2, AoFb, X2b, 1536, 3072, 768);
    mink_ln<1><<<2048, blk, 0, stream>>>(xb, AoFb, X2b, g2t, b2t, g2s, b2s,
                                         out, nullptr, NROW);
}

// Round 14
// 177.047 us; speedup vs baseline: 1.0886x; 1.0032x over previous
//
#include <hip/hip_runtime.h>
#include <cstddef>
#include <cstdint>

#define D_EMB  768
#define NHEAD  12
#define HDIM   64
#define THEAD  32
#define SEQ    2048
#define BATCH  2
#define NROW   (BATCH*SEQ)   // 4096
#define HID4   3072

typedef unsigned short u16;
typedef __bf16 bf16x8 __attribute__((ext_vector_type(8)));
typedef float  f32x4  __attribute__((ext_vector_type(4)));
typedef unsigned short u16x8 __attribute__((ext_vector_type(8)));

__device__ __forceinline__ u16 f2bf(float f) {
    unsigned u = __builtin_bit_cast(unsigned, f);
    return (u16)((u + 0x7FFFu + ((u >> 16) & 1u)) >> 16);
}
__device__ __forceinline__ float bf2f(u16 h) {
    return __builtin_bit_cast(float, (unsigned)h << 16);
}
__device__ __forceinline__ u16 cvt_bf(float f) {
    return __builtin_bit_cast(u16, (__bf16)f);
}

// global -> LDS direct copy, 16B per lane. LDS dst is wave-uniform base;
// HW writes base + lane*16. Global src is per-lane.
__device__ __forceinline__ void gload_lds16(const void* g, void* l) {
    __builtin_amdgcn_global_load_lds(
        reinterpret_cast<const __attribute__((address_space(1))) void*>(
            reinterpret_cast<uintptr_t>(g)),
        reinterpret_cast<__attribute__((address_space(3))) void*>(
            (uint32_t)reinterpret_cast<uintptr_t>(l)),
        16, 0, 0);
}

// ---------------------------------------------------------------------------
// Fused prep: all weight transposes + x cast + bias concat in one launch.
// ---------------------------------------------------------------------------
__device__ __forceinline__ void tcast(float (*t)[33], const float* __restrict__ W,
                                      u16* __restrict__ WT, int K, int M,
                                      int mt, int kt)
{
    const int m0 = mt * 32, k0 = kt * 32;
    const int tx = threadIdx.x & 31, ty = threadIdx.x >> 5;
#pragma unroll
    for (int i = 0; i < 32; i += 8)
        t[ty + i][tx] = W[(size_t)(k0 + ty + i) * M + m0 + tx];
    __syncthreads();
#pragma unroll
    for (int i = 0; i < 32; i += 8)
        WT[(size_t)(m0 + ty + i) * K + k0 + tx] = f2bf(t[tx][ty + i]);
}

__global__ __launch_bounds__(256)
void prep(const float* __restrict__ Wq, const float* __restrict__ Wk,
          const float* __restrict__ Wv, const float* __restrict__ Wo,
          const float* __restrict__ W1, const float* __restrict__ W2,
          const float* __restrict__ bq, const float* __restrict__ bk,
          const float* __restrict__ bv, const float* __restrict__ x,
          u16* __restrict__ WqkvoT, u16* __restrict__ W1T,
          u16* __restrict__ W2T, u16* __restrict__ xb,
          float* __restrict__ bqkv)
{
    __shared__ float t[32][33];
    const int bid = blockIdx.x;
    if (bid < 2304) {                       // Wq/Wk/Wv/Wo 768x768 -> [z*768+m][k]
        const int z = bid / 576, r = bid % 576;
        const float* W = z == 0 ? Wq : z == 1 ? Wk : z == 2 ? Wv : Wo;
        tcast(t, W, WqkvoT + (size_t)z * 768 * 768, 768, 768, r % 24, r / 24);
    } else if (bid < 4608) {                // W1 [768][3072] -> [3072][768]
        const int r = bid - 2304;
        tcast(t, W1, W1T, 768, 3072, r % 96, r / 96);
    } else if (bid < 6912) {                // W2 [3072][768] -> [768][3072]
        const int r = bid - 4608;
        tcast(t, W2, W2T, 3072, 768, r % 24, r / 24);
    } else if (bid < 8448) {                // cast x -> bf16
        const int i = (bid - 6912) * 2048 + threadIdx.x * 8;
        const float4 a = *reinterpret_cast<const float4*>(x + i);
        const float4 b = *reinterpret_cast<const float4*>(x + i + 4);
        u16x8 h;
        h[0] = f2bf(a.x); h[1] = f2bf(a.y); h[2] = f2bf(a.z); h[3] = f2bf(a.w);
        h[4] = f2bf(b.x); h[5] = f2bf(b.y); h[6] = f2bf(b.z); h[7] = f2bf(b.w);
        *reinterpret_cast<u16x8*>(xb + i) = h;
    } else {                                // concat qkv bias
        const int i = (bid - 8448) * 256 + threadIdx.x;
        if (i < 2304)
            bqkv[i] = i < 768 ? bq[i] : (i < 1536 ? bk[i - 768] : bv[i - 1536]);
    }
}

// ---------------------------------------------------------------------------
// bf16 MFMA GEMM: C[Mr x N] = A[Mr x K] @ B[N x K]^T + bias
// 128x128 tile, BK=32, 4 waves, double-buffered LDS.
// EPI: 2 = gelu+bf16 out, 3 = QKV mode (QK bf16 [row][1536], V written
//      transposed AND token-permuted to VT[b][h][d][kt + p(tok)]).
// ---------------------------------------------------------------------------
template<int EPI>
__global__ __launch_bounds__(256)
void gemm_bf16(const u16* __restrict__ A, const u16* __restrict__ B,
               const float* __restrict__ bias, void* __restrict__ Cp,
               u16* __restrict__ VTp, int K, int N)
{
    __shared__ u16 As[2][128 * 32];
    __shared__ u16 Bs[2][128 * 32];
    const int tid  = threadIdx.x;
    const int lane = tid & 63;
    const int w    = tid >> 6;
    const int m0 = blockIdx.x * 128, n0 = blockIdx.y * 128;
    const int wr = (w >> 1) << 6, wc = (w & 1) << 6;

    const int seg0 = (w << 11) + lane * 16;
    const int row0 = seg0 >> 6, cb0 = (seg0 & 63) >> 1;
    const int seg1 = seg0 + 1024;
    const int row1 = seg1 >> 6, cb1 = (seg1 & 63) >> 1;
    const u16* a0 = A + (size_t)(m0 + row0) * K + cb0;
    const u16* a1 = A + (size_t)(m0 + row1) * K + cb1;
    const u16* b0 = B + (size_t)(n0 + row0) * K + cb0;
    const u16* b1 = B + (size_t)(n0 + row1) * K + cb1;
    const int lo0 = (w * 2 + 0) << 9;
    const int lo1 = (w * 2 + 1) << 9;

    int aIdx[4], bIdx[4];
#pragma unroll
    for (int i = 0; i < 4; ++i) {
        aIdx[i] = (wr + i * 16 + (lane & 15)) * 32 + ((lane >> 4) << 3);
        bIdx[i] = (wc + i * 16 + (lane & 15)) * 32 + ((lane >> 4) << 3);
    }

    f32x4 acc[4][4];
#pragma unroll
    for (int i = 0; i < 4; ++i)
#pragma unroll
        for (int j = 0; j < 4; ++j)
#pragma unroll
            for (int q = 0; q < 4; ++q) acc[i][j][q] = 0.f;

    gload_lds16(a0, &As[0][lo0]);
    gload_lds16(a1, &As[0][lo1]);
    gload_lds16(b0, &Bs[0][lo0]);
    gload_lds16(b1, &Bs[0][lo1]);
    __syncthreads();

    int cur = 0;
    for (int k0 = 0; k0 < K; k0 += 32) {
        if (k0 + 32 < K) {
            gload_lds16(a0 + k0 + 32, &As[cur ^ 1][lo0]);
            gload_lds16(a1 + k0 + 32, &As[cur ^ 1][lo1]);
            gload_lds16(b0 + k0 + 32, &Bs[cur ^ 1][lo0]);
            gload_lds16(b1 + k0 + 32, &Bs[cur ^ 1][lo1]);
        }
        bf16x8 af[4], bv[4];
#pragma unroll
        for (int i = 0; i < 4; ++i)
            af[i] = *reinterpret_cast<const bf16x8*>(&As[cur][aIdx[i]]);
#pragma unroll
        for (int j = 0; j < 4; ++j)
            bv[j] = *reinterpret_cast<const bf16x8*>(&Bs[cur][bIdx[j]]);
#pragma unroll
        for (int i = 0; i < 4; ++i)
#pragma unroll
            for (int j = 0; j < 4; ++j)
                acc[i][j] = __builtin_amdgcn_mfma_f32_16x16x32_bf16(
                    af[i], bv[j], acc[i][j], 0, 0, 0);
        __syncthreads();
        cur ^= 1;
    }

#pragma unroll
    for (int i = 0; i < 4; ++i) {
#pragma unroll
        for (int q = 0; q < 4; ++q) {
            const int row = m0 + wr + i * 16 + ((lane >> 4) << 2) + q;
#pragma unroll
            for (int j = 0; j < 4; ++j) {
                const int col = n0 + wc + j * 16 + (lane & 15);
                float v = acc[i][j][q] + bias[col];
                if (EPI == 2) {
                    // gelu(tanh form) == v * sigmoid(2*0.79788456*(v+0.044715 v^3))
                    const float z = 1.5957691216057308f *
                                    (v + 0.044715f * v * v * v);
                    const float e = __builtin_amdgcn_exp2f(z * -1.4426950408889634f);
                    v = v * __builtin_amdgcn_rcpf(1.f + e);
                    ((u16*)Cp)[(size_t)row * N + col] = cvt_bf(v);
                } else {   // EPI == 3: QKV
                    if (n0 < 1536) {
                        ((u16*)Cp)[(size_t)row * 1536 + col] = cvt_bf(v);
                    } else {
                        const int c2 = col - 1536;
                        const int hh = c2 >> 6, dd = c2 & 63;
                        const int bb = row >> 11, tok = row & 2047;
                        const int t = tok & 63;
                        const int p = ((t & 15) << 2) | (t >> 4);
                        VTp[((size_t)(bb * NHEAD + hh) * HDIM + dd) * SEQ
                            + (tok & ~63) + p] = cvt_bf(v);
                    }
                }
            }
        }
    }
}

// ---------------------------------------------------------------------------
// BM=64 x BN=128 split-K GEMM for N=768 shapes, bf16 partial outputs.
// grid.z = 2: z=0 computes K-half 0 (+bias) -> C0; z=1 K-half 1 -> C1.
// Consumer (mink_ln) adds bf2f(C0) + bf2f(C1).
// ---------------------------------------------------------------------------
__global__ __launch_bounds__(256)
void gemm_n64(const u16* __restrict__ A, const u16* __restrict__ B,
              const float* __restrict__ bias, u16* __restrict__ C0,
              u16* __restrict__ C1, int Khalf, int Ktot, int N)
{
    __shared__ u16 As[2][64 * 32];
    __shared__ u16 Bs[2][128 * 32];
    const int tid  = threadIdx.x;
    const int lane = tid & 63;
    const int w    = tid >> 6;
    const int l15  = lane & 15;
    const int g    = lane >> 4;
    const int m0 = blockIdx.x * 64, n0 = blockIdx.y * 128;
    const int zz = blockIdx.z;
    const int kbase = zz * Khalf;
    u16* __restrict__ C = zz ? C1 : C0;

    const int segA = (w << 10) + lane * 16;
    const int rowA = segA >> 6, cbA = (segA & 63) >> 1;
    const u16* aP = A + (size_t)(m0 + rowA) * Ktot + kbase + cbA;
    const int loA = w << 9;
    const int seg0 = (w << 11) + lane * 16;
    const int row0 = seg0 >> 6, cb0 = (seg0 & 63) >> 1;
    const int seg1 = seg0 + 1024;
    const int row1 = seg1 >> 6, cb1 = (seg1 & 63) >> 1;
    const u16* b0 = B + (size_t)(n0 + row0) * Ktot + kbase + cb0;
    const u16* b1 = B + (size_t)(n0 + row1) * Ktot + kbase + cb1;
    const int lo0 = w << 10, lo1 = (w << 10) + 512;

    int aIdx[4], bIdx[2];
#pragma unroll
    for (int i = 0; i < 4; ++i) aIdx[i] = (i * 16 + l15) * 32 + (g << 3);
#pragma unroll
    for (int j = 0; j < 2; ++j) bIdx[j] = ((w << 5) + j * 16 + l15) * 32 + (g << 3);

    f32x4 acc[4][2];
#pragma unroll
    for (int i = 0; i < 4; ++i)
#pragma unroll
        for (int j = 0; j < 2; ++j)
#pragma unroll
            for (int q = 0; q < 4; ++q) acc[i][j][q] = 0.f;

    gload_lds16(aP, &As[0][loA]);
    gload_lds16(b0, &Bs[0][lo0]);
    gload_lds16(b1, &Bs[0][lo1]);
    __syncthreads();

    int cur = 0;
    for (int k0 = 0; k0 < Khalf; k0 += 32) {
        if (k0 + 32 < Khalf) {
            gload_lds16(aP + k0 + 32, &As[cur ^ 1][loA]);
            gload_lds16(b0 + k0 + 32, &Bs[cur ^ 1][lo0]);
            gload_lds16(b1 + k0 + 32, &Bs[cur ^ 1][lo1]);
        }
        bf16x8 af[4], bv[2];
#pragma unroll
        for (int i = 0; i < 4; ++i)
            af[i] = *reinterpret_cast<const bf16x8*>(&As[cur][aIdx[i]]);
#pragma unroll
        for (int j = 0; j < 2; ++j)
            bv[j] = *reinterpret_cast<const bf16x8*>(&Bs[cur][bIdx[j]]);
#pragma unroll
        for (int i = 0; i < 4; ++i)
#pragma unroll
            for (int j = 0; j < 2; ++j)
                acc[i][j] = __builtin_amdgcn_mfma_f32_16x16x32_bf16(
                    af[i], bv[j], acc[i][j], 0, 0, 0);
        __syncthreads();
        cur ^= 1;
    }

#pragma unroll
    for (int i = 0; i < 4; ++i) {
#pragma unroll
        for (int q = 0; q < 4; ++q) {
            const int row = m0 + i * 16 + (g << 2) + q;
#pragma unroll
            for (int j = 0; j < 2; ++j) {
                const int col = n0 + (w << 5) + j * 16 + l15;
                const float bb = zz ? 0.f : bias[col];
                C[(size_t)row * N + col] = cvt_bf(acc[i][j][q] + bb);
            }
        }
    }
}

// ---------------------------------------------------------------------------
// MFMA flash attention: r13 kernel + 2 q-subtiles per wave (K/V fragments
// read once, used twice -> per-q LDS traffic halved) + split-KV z=2 to keep
// 768 blocks (occupancy unchanged). Unnormalized bf16 O-partials + f32 sums,
// merged by attn_merge. Same swizzle/P-layout/ones-MFMA/setprio as r13.
// ---------------------------------------------------------------------------
#define SM_SCALE 0.18033688011112042f   // log2(e)/8

__global__ __launch_bounds__(256)
void attn_mfma(const u16* __restrict__ QK, const u16* __restrict__ VT,
               u16* __restrict__ O0, u16* __restrict__ O1,
               float* __restrict__ Sp)
{
    __shared__ u16 Ks[2][64 * 64];
    __shared__ u16 Vs[2][64 * 64];
    __shared__ u16 Ps[128 * 72];   // 128 q-rows, stride 72 u16

    const int tid  = threadIdx.x;
    const int lane = tid & 63;
    const int w    = tid >> 6;           // 0..3
    const int l15  = lane & 15;
    const int g    = lane >> 4;
    const int bh   = blockIdx.x;
    const int b    = bh / NHEAD, h = bh % NHEAD;
    const int q0   = blockIdx.y * 128;
    const int z    = blockIdx.z;
    const int keybase = z * 1024;
    const int bS   = b * SEQ;

    // ---- Q A-fragments, 2 q-subtiles, pre-scaled (eta: kk==0 negative) ----
    bf16x8 aq[2][2];
#pragma unroll
    for (int qb = 0; qb < 2; ++qb) {
        const u16* Qg = QK + (size_t)(bS + q0 + w * 32 + qb * 16 + l15) * 1536
                        + h * HDIM;
#pragma unroll
        for (int kk = 0; kk < 2; ++kk) {
            const u16x8 hq = *reinterpret_cast<const u16x8*>(Qg + kk * 32 + g * 8);
            const float sc = (kk == 0) ? -SM_SCALE : SM_SCALE;
            u16x8 hs;
#pragma unroll
            for (int j = 0; j < 8; ++j)
                hs[j] = cvt_bf(bf2f(hq[j]) * sc);
            aq[qb][kk] = __builtin_bit_cast(bf16x8, hs);
        }
    }

    // ---- staging pointers (chunk-swizzled global src, linear LDS dst) ----
    const int rl = lane >> 3;
    const int cs = ((lane & 7) ^ rl) << 3;
    const u16* pK = QK + (size_t)(bS + keybase + 16 * w + rl) * 1536
                    + 768 + h * HDIM + cs;
    const u16* pV = VT + ((size_t)(b * NHEAD + h) * HDIM + 16 * w + rl) * SEQ
                    + keybase + cs;

    int swz[2];
#pragma unroll
    for (int kk = 0; kk < 2; ++kk)
        swz[kk] = ((kk * 4 + g) ^ (l15 & 7)) << 3;

    bf16x8 vones;
    {
        u16x8 o16;
#pragma unroll
        for (int j = 0; j < 8; ++j) o16[j] = 0x3F80u;
        vones = __builtin_bit_cast(bf16x8, o16);
    }

    f32x4 accO[2][4];
#pragma unroll
    for (int qb = 0; qb < 2; ++qb)
#pragma unroll
        for (int n = 0; n < 4; ++n)
#pragma unroll
            for (int q = 0; q < 4; ++q) accO[qb][n][q] = 0.f;
    f32x4 accS[2];
#pragma unroll
    for (int qb = 0; qb < 2; ++qb)
#pragma unroll
        for (int q = 0; q < 4; ++q) accS[qb][q] = 0.f;

#define ATTN_STAGE(c, kt)                                                   \
    do {                                                                    \
        u16* dK = &Ks[c][w * 1024];                                         \
        u16* dV = &Vs[c][w * 1024];                                         \
        gload_lds16(pK + (size_t)(kt) * 1536,       dK);                    \
        gload_lds16(pK + (size_t)((kt) + 8) * 1536, dK + 512);              \
        gload_lds16(pV + (kt),           dV);                               \
        gload_lds16(pV + (kt) + 8 * SEQ, dV + 512);                         \
    } while (0)

    ATTN_STAGE(0, 0);
    __syncthreads();
    int cur = 0;

    for (int kt = 0; kt < 1024; kt += 64) {
        if (kt + 64 < 1024) ATTN_STAGE(cur ^ 1, kt + 64);

        // ---- S = (Q*eta*scale) K^T: K frags read once, used for both qb ----
        f32x4 sac[2][4];
        __builtin_amdgcn_s_setprio(1);
#pragma unroll
        for (int n = 0; n < 4; ++n) {
#pragma unroll
            for (int kk = 0; kk < 2; ++kk) {
                const bf16x8 bk = *reinterpret_cast<const bf16x8*>(
                    &Ks[cur][(n * 16 + l15) * 64 + swz[kk]]);
#pragma unroll
                for (int qb = 0; qb < 2; ++qb) {
                    if (kk == 0) {
#pragma unroll
                        for (int q = 0; q < 4; ++q) sac[qb][n][q] = 0.f;
                    }
                    sac[qb][n] = __builtin_amdgcn_mfma_f32_16x16x32_bf16(
                        aq[qb][kk], bk, sac[qb][n], 0, 0, 0);
                }
            }
        }
        __builtin_amdgcn_s_setprio(0);

        // ---- P = exp2(sac), packed b64 (token-permuted layout) ----
#pragma unroll
        for (int qb = 0; qb < 2; ++qb)
#pragma unroll
            for (int r4 = 0; r4 < 4; ++r4) {
                const int prow = w * 32 + qb * 16 + (g << 2) + r4;
                const float sv0 = __builtin_amdgcn_exp2f(sac[qb][0][r4]);
                const float sv1 = __builtin_amdgcn_exp2f(sac[qb][1][r4]);
                const float sv2 = __builtin_amdgcn_exp2f(sac[qb][2][r4]);
                const float sv3 = __builtin_amdgcn_exp2f(sac[qb][3][r4]);
                ushort4 pk4;
                pk4.x = cvt_bf(sv0);
                pk4.y = cvt_bf(sv1);
                pk4.z = cvt_bf(sv2);
                pk4.w = cvt_bf(sv3);
                *reinterpret_cast<ushort4*>(&Ps[prow * 72 + (l15 << 2)]) = pk4;
            }

        // ---- O += P @ V: V frags read once, used for both qb ----
        bf16x8 pa[2][2];
#pragma unroll
        for (int qb = 0; qb < 2; ++qb)
#pragma unroll
            for (int kk = 0; kk < 2; ++kk)
                pa[qb][kk] = *reinterpret_cast<const bf16x8*>(
                    &Ps[(w * 32 + qb * 16 + l15) * 72 + kk * 32 + g * 8]);
        __builtin_amdgcn_s_setprio(1);
#pragma unroll
        for (int n = 0; n < 4; ++n) {
#pragma unroll
            for (int kk = 0; kk < 2; ++kk) {
                const bf16x8 bv = *reinterpret_cast<const bf16x8*>(
                    &Vs[cur][(n * 16 + l15) * 64 + swz[kk]]);
#pragma unroll
                for (int qb = 0; qb < 2; ++qb)
                    accO[qb][n] = __builtin_amdgcn_mfma_f32_16x16x32_bf16(
                        pa[qb][kk], bv, accO[qb][n], 0, 0, 0);
            }
        }
#pragma unroll
        for (int qb = 0; qb < 2; ++qb)
#pragma unroll
            for (int kk = 0; kk < 2; ++kk)
                accS[qb] = __builtin_amdgcn_mfma_f32_16x16x32_bf16(
                    pa[qb][kk], vones, accS[qb], 0, 0, 0);
        __builtin_amdgcn_s_setprio(0);
        __syncthreads();
        cur ^= 1;
    }

    // ---- store unnormalized bf16 O-partials + f32 sums ----
    u16* __restrict__ Oz = z ? O1 : O0;
#pragma unroll
    for (int qb = 0; qb < 2; ++qb)
#pragma unroll
        for (int r4 = 0; r4 < 4; ++r4) {
            const int qr = q0 + w * 32 + qb * 16 + (g << 2) + r4;
#pragma unroll
            for (int n = 0; n < 4; ++n)
                Oz[(size_t)(bS + qr) * D_EMB + h * HDIM + n * 16 + l15]
                    = cvt_bf(accO[qb][n][r4]);
            if (l15 == 0)
                Sp[(size_t)z * (BATCH * NHEAD * SEQ) + (b * NHEAD + h) * SEQ + qr]
                    = accS[qb][r4];
        }
#undef ATTN_STAGE
}

// ---------------------------------------------------------------------------
// Merge split-KV partials: Ab = (O0 + O1) / (S0 + S1), bf16 out.
// ---------------------------------------------------------------------------
__global__ __launch_bounds__(256)
void attn_merge(const u16* __restrict__ O0, const u16* __restrict__ O1,
                const float* __restrict__ Sp, u16* __restrict__ Ab)
{
    const int gid = blockIdx.x * 256 + threadIdx.x;   // ND/8 threads
    const size_t e = (size_t)gid * 8;
    const int row = gid / 96;            // 96 8-chunks per 768-row
    const int cc  = gid % 96;
    const int h   = cc >> 3;
    const int b   = row >> 11, q = row & 2047;
    const int si  = (b * NHEAD + h) * SEQ + q;
    const float s = Sp[si] + Sp[(size_t)(BATCH * NHEAD * SEQ) + si];
    const float inv = __builtin_amdgcn_rcpf(s);
    const u16x8 a = *reinterpret_cast<const u16x8*>(O0 + e);
    const u16x8 c = *reinterpret_cast<const u16x8*>(O1 + e);
    u16x8 o;
#pragma unroll
    for (int j = 0; j < 8; ++j)
        o[j] = cvt_bf((bf2f(a[j]) + bf2f(c[j])) * inv);
    *reinterpret_cast<u16x8*>(Ab + e) = o;
}

// ---------------------------------------------------------------------------
// Minkowski LN over 384/384 split with TWO bf16 residual inputs:
// Out = LN(X + R1 + R2) * g + b. 2-wide vectorized accesses.
// XBF: X input is bf16. Out (fp32) / OutB (bf16) optional.
// ---------------------------------------------------------------------------
template<int XBF>
__global__ __launch_bounds__(256)
void mink_ln(const void* __restrict__ Xp, const u16* __restrict__ R1,
             const u16* __restrict__ R2,
             const float* __restrict__ gt, const float* __restrict__ bt,
             const float* __restrict__ gs, const float* __restrict__ bs,
             float* __restrict__ Out, u16* __restrict__ OutB, int nrows)
{
    const int wid  = (int)((blockIdx.x * 256 + threadIdx.x) >> 6);
    const int lane = threadIdx.x & 63;
    const int row  = wid >> 1, half = wid & 1;
    if (row >= nrows) return;

    const float* g  = half ? gs : gt;
    const float* bb = half ? bs : bt;
    const size_t base = (size_t)row * D_EMB + half * 384;

    float v[6];
    float sum = 0.f;
#pragma unroll
    for (int i = 0; i < 3; ++i) {
        const size_t e = base + i * 128 + lane * 2;
        float x0, x1;
        if (XBF) {
            const unsigned xv = *reinterpret_cast<const unsigned*>(
                (const u16*)Xp + e);
            x0 = bf2f((u16)xv); x1 = bf2f((u16)(xv >> 16));
        } else {
            const float2 xf = *reinterpret_cast<const float2*>(
                (const float*)Xp + e);
            x0 = xf.x; x1 = xf.y;
        }
        const unsigned r1 = *reinterpret_cast<const unsigned*>(R1 + e);
        const unsigned r2 = *reinterpret_cast<const unsigned*>(R2 + e);
        const float t0 = x0 + bf2f((u16)r1) + bf2f((u16)r2);
        const float t1 = x1 + bf2f((u16)(r1 >> 16)) + bf2f((u16)(r2 >> 16));
        v[2 * i] = t0; v[2 * i + 1] = t1;
        sum += t0 + t1;
    }
#pragma unroll
    for (int off = 32; off; off >>= 1) sum += __shfl_xor(sum, off);
    const float mean = sum * (1.f / 384.f);

    float ss = 0.f;
#pragma unroll
    for (int i = 0; i < 6; ++i) { const float d = v[i] - mean; ss += d * d; }
#pragma unroll
    for (int off = 32; off; off >>= 1) ss += __shfl_xor(ss, off);
    const float rstd = rsqrtf(ss * (1.f / 384.f) + 1e-5f);

#pragma unroll
    for (int i = 0; i < 3; ++i) {
        const int e = i * 128 + lane * 2;
        const float o0 = (v[2 * i]     - mean) * rstd * g[e]     + bb[e];
        const float o1 = (v[2 * i + 1] - mean) * rstd * g[e + 1] + bb[e + 1];
        if (Out) {
            float2 of; of.x = o0; of.y = o1;
            *reinterpret_cast<float2*>(Out + base + e) = of;
        }
        if (OutB) {
            const unsigned pk = (unsigned)cvt_bf(o0) |
                                ((unsigned)cvt_bf(o1) << 16);
            *reinterpret_cast<unsigned*>(OutB + base + e) = pk;
        }
    }
}

// ---------------------------------------------------------------------------
extern "C" void kernel_launch(void* const* d_in, const int* in_sizes, int n_in,
                              void* d_out, int out_size, void* d_ws, size_t ws_size,
                              hipStream_t stream)
{
    const float* x   = (const float*)d_in[0];
    const float* Wq  = (const float*)d_in[1];
    const float* bq  = (const float*)d_in[2];
    const float* Wk  = (const float*)d_in[3];
    const float* bk  = (const float*)d_in[4];
    const float* Wv  = (const float*)d_in[5];
    const float* bv  = (const float*)d_in[6];
    const float* Wo  = (const float*)d_in[7];
    const float* bo  = (const float*)d_in[8];
    const float* g1t = (const float*)d_in[9];
    const float* b1t = (const float*)d_in[10];
    const float* g1s = (const float*)d_in[11];
    const float* b1s = (const float*)d_in[12];
    const float* W1  = (const float*)d_in[13];
    const float* bb1 = (const float*)d_in[14];
    const float* W2  = (const float*)d_in[15];
    const float* bb2 = (const float*)d_in[16];
    const float* g2t = (const float*)d_in[17];
    const float* b2t = (const float*)d_in[18];
    const float* g2s = (const float*)d_in[19];
    const float* b2s = (const float*)d_in[20];
    float* out = (float*)d_out;

    const size_t ND = (size_t)NROW * D_EMB;   // 3,145,728
    u16* WqkvoT = (u16*)d_ws;                 // [3072][768] rows q,k,v,o
    u16* W1T = WqkvoT + 2359296;              // [3072][768]
    u16* W2T = W1T + 2359296;                 // [768][3072]
    u16* xb  = W2T + 2359296;                 // ND (x bf16, then X1 bf16)
    u16* QKb = xb + ND;                       // [4096][1536] q|k
    u16* VTb = QKb + (size_t)NROW * 1536;     // [2][12][64][2048] (tok-permuted)
    u16* Ab  = VTb + ND;                      // ND (attn out bf16)
    u16* Hb  = QKb;                           // [4096][3072] over QKb+VTb+Ab
    float* bqkv = (float*)(Ab + ND);          // 2304 f32, dead before attn
    u16* Op0 = (u16*)(Ab + ND);               // attn O-partial z=0
    u16* Op1 = Op0 + ND;                      // attn O-partial z=1
    float* Sp = (float*)(Op1 + ND);           // 2 x 49152 f32 sums
    u16* AoFb = Op0;                          // Wo/W2 partial#1 (Op0 dead post-merge)
    u16* QKfb = (u16*)QKb;                    // Wo partial#2 (QK dead post-attn)
    u16* X2b  = Op1;                          // W2 partial#2 (Op1 dead post-LN1)

    const dim3 blk(256);

    prep<<<8457, blk, 0, stream>>>(Wq, Wk, Wv, Wo, W1, W2, bq, bk, bv, x,
                                   WqkvoT, W1T, W2T, xb, bqkv);

    // fused QKV projection (writes QKb + transposed, token-permuted V)
    gemm_bf16<3><<<dim3(32, 18), blk, 0, stream>>>(xb, WqkvoT, bqkv, QKb, VTb,
                                                   768, 2304);
    // split-KV attention (128 q-rows/block, 2 kv-halves) + merge
    attn_mfma<<<dim3(BATCH * NHEAD, SEQ / 128, 2), blk, 0, stream>>>(
        QKb, VTb, Op0, Op1, Sp);
    attn_merge<<<(int)(ND / 8 / 256), blk, 0, stream>>>(Op0, Op1, Sp, Ab);

    // Wo projection, split-K=2, bf16 partials: p1 -> AoFb (+bias), p2 -> QKfb
    gemm_n64<<<dim3(64, 6, 2), blk, 0, stream>>>(
        Ab, WqkvoT + (size_t)2304 * 768, bo, AoFb, QKfb, 384, 768, 768);
    // LN1: X1 (bf16 only) -> xb
    mink_ln<0><<<2048, blk, 0, stream>>>(x, AoFb, QKfb, g1t, b1t, g1s, b1s,
                                         nullptr, xb, NROW);
    gemm_bf16<2><<<dim3(32, 24), blk, 0, stream>>>(xb, W1T, bb1, Hb, nullptr,
                                                   768, 3072);
    // W2, split-K=2, bf16 partials: p1 -> AoFb (+bias), p2 -> X2b
    gemm_n64<<<dim3(64, 6, 2), blk, 0, stream>>>(
        Hb, W2T, bb2, AoFb, X2b, 1536, 3072, 768);
    mink_ln<1><<<2048, blk, 0, stream>>>(xb, AoFb, X2b, g2t, b2t, g2s, b2s,
                                         out, nullptr, NROW);
}